// Round 16
// baseline (242.418 us; speedup 1.0000x reference)
//
#include <hip/hip_runtime.h>

#define BN 4
#define CC 256
#define NN 4096
#define CR 32
#define OCH 128

typedef float f32x4 __attribute__((ext_vector_type(4)));
typedef short short8 __attribute__((ext_vector_type(8)));
typedef unsigned short u16x8 __attribute__((ext_vector_type(8)));
typedef unsigned short u16x4 __attribute__((ext_vector_type(4)));

__device__ __forceinline__ unsigned short f2b(float f) {
  unsigned u = __builtin_bit_cast(unsigned, f);
  u += 0x7fff + ((u >> 16) & 1);
  return (unsigned short)(u >> 16);
}
__device__ __forceinline__ float b2f(unsigned short h) {
  unsigned u = ((unsigned)h) << 16;
  return __builtin_bit_cast(float, u);
}

// ---------------------------------------------------------------------------
// cast wq / wv to bf16
__global__ __launch_bounds__(256) void k_wcast(const float* __restrict__ wq,
    const float* __restrict__ wv, unsigned short* __restrict__ wqb,
    unsigned short* __restrict__ wvb) {
  const int gid = (blockIdx.x * 256 + threadIdx.x) * 4;
  const float* src = blockIdx.y ? wv : wq;
  unsigned short* dst = blockIdx.y ? wvb : wqb;
  const float4 v = *(const float4*)(src + gid);
  u16x4 o; o[0] = f2b(v.x); o[1] = f2b(v.y); o[2] = f2b(v.z); o[3] = f2b(v.w);
  *(u16x4*)(dst + gid) = o;
}

// ---------------------------------------------------------------------------
// transpose+cast x[b][c][n] f32 -> xt[b][n][c] bf16, fused partial spatial sum
__global__ __launch_bounds__(256) void k_xt(const float* __restrict__ x,
    unsigned short* __restrict__ xt, float* __restrict__ part2) {
  __shared__ unsigned short T[64][65];
  __shared__ float red[256];
  const int b = blockIdx.z, c0 = blockIdx.y * 64, n0 = blockIdx.x * 64;
  const int t = threadIdx.x;
  float s = 0.f;
  for (int idx = t; idx < 4096; idx += 256) {
    int i = idx >> 6, j = idx & 63;
    const float v = x[((size_t)(b * CC + c0 + i)) * NN + n0 + j];
    s += v;
    T[i][j] = f2b(v);
  }
  __syncthreads();
  for (int idx = t; idx < 4096; idx += 256) {
    int j = idx >> 6, i = idx & 63;
    xt[((size_t)(b * NN + n0 + j)) * CC + c0 + i] = T[i][j];
  }
  red[t] = s;
  __syncthreads();
  for (int d = 128; d > 0; d >>= 1) {
    if (t < d) red[t] += red[t + d];
    __syncthreads();
  }
  if (t == 0) part2[b * 256 + blockIdx.y * 64 + blockIdx.x] = red[0];
}

__global__ void k_spatial2(const float* __restrict__ part2, float* __restrict__ spatial) {
  const int b = blockIdx.x;
  const int t = threadIdx.x;
  __shared__ float red[256];
  red[t] = part2[b * 256 + t];
  __syncthreads();
  for (int d = 128; d > 0; d >>= 1) {
    if (t < d) red[t] += red[t + d];
    __syncthreads();
  }
  if (t == 0) spatial[b] = red[0] * (1.0f / ((float)CC * NN));
}

// ---------------------------------------------------------------------------
// MFMA projection GEMM: out[b][c][n] = bias[c] + sum_j W[c][j] xt[b][n][j]
__global__ __launch_bounds__(256) void k_projm(const unsigned short* __restrict__ xt,
    const unsigned short* __restrict__ wqb, const float* __restrict__ bq,
    const unsigned short* __restrict__ wvb, const float* __restrict__ bv,
    unsigned short* __restrict__ q1b, unsigned short* __restrict__ Vb) {
  const int b = blockIdx.y, n0 = blockIdx.x * 32, which = blockIdx.z;
  const unsigned short* W = which ? wvb : wqb;
  const float* bias = which ? bv : bq;
  unsigned short* out = which ? Vb : q1b;
  const int t = threadIdx.x;
  const int w = t >> 6, l = t & 63;
  const int lo = l & 15, hi = l >> 4;
  const int oc0 = w * 64;
  f32x4 acc[4][2];
#pragma unroll
  for (int ct = 0; ct < 4; ++ct)
#pragma unroll
    for (int nt = 0; nt < 2; ++nt) acc[ct][nt] = (f32x4){0.f, 0.f, 0.f, 0.f};
  const unsigned short* wb = W + (size_t)(oc0 + lo) * CC + hi * 8;
  const unsigned short* xb = xt + ((size_t)(b * NN + n0 + lo)) * CC + hi * 8;
#pragma unroll
  for (int k0 = 0; k0 < CC; k0 += 32) {
    short8 aw[4], bx[2];
#pragma unroll
    for (int ct = 0; ct < 4; ++ct) aw[ct] = *(const short8*)(wb + ct * 16 * CC + k0);
#pragma unroll
    for (int nt = 0; nt < 2; ++nt) bx[nt] = *(const short8*)(xb + nt * 16 * CC + k0);
#pragma unroll
    for (int ct = 0; ct < 4; ++ct)
#pragma unroll
      for (int nt = 0; nt < 2; ++nt)
        acc[ct][nt] = __builtin_amdgcn_mfma_f32_16x16x32_bf16(aw[ct], bx[nt], acc[ct][nt], 0, 0, 0);
  }
#pragma unroll
  for (int ct = 0; ct < 4; ++ct) {
#pragma unroll
    for (int r = 0; r < 4; ++r) {
      const int c = oc0 + ct * 16 + hi * 4 + r;
      const float bvv = bias[c];
#pragma unroll
      for (int nt = 0; nt < 2; ++nt)
        out[((size_t)(b * CC + c)) * NN + n0 + nt * 16 + lo] = f2b(acc[ct][nt][r] + bvv);
    }
  }
}

// ---------------------------------------------------------------------------
// grouped conv1d (bf16 in, f32 out), vectorized: thread = 8 consecutive n
__global__ __launch_bounds__(256) void k_adj1(const unsigned short* __restrict__ q1,
    const float* __restrict__ w1, const float* __restrict__ b1,
    float* __restrict__ q2) {
  const int gid = blockIdx.x * 256 + threadIdx.x;   // B*32*(N/8) = 65536
  const int n8 = gid & 511;
  const int o = (gid >> 9) & 31;
  const int b = gid >> 14;
  const int n0 = n8 * 8;
  const unsigned short* base = q1 + ((size_t)b * CC + o * 8) * NN;
  float accv[8];
  const float bias = b1[o];
#pragma unroll
  for (int j = 0; j < 8; ++j) accv[j] = bias;
#pragma unroll
  for (int i = 0; i < 8; ++i) {
    const unsigned short* r = base + (size_t)i * NN;
    const u16x8 v = *(const u16x8*)(r + n0);
    float f[10];
    f[0] = (n0 > 0) ? b2f(r[n0 - 1]) : 0.f;
#pragma unroll
    for (int j = 0; j < 8; ++j) f[j + 1] = b2f(v[j]);
    f[9] = (n0 + 8 < NN) ? b2f(r[n0 + 8]) : 0.f;
    const float wa = w1[o * 24 + i * 3 + 0];
    const float wb = w1[o * 24 + i * 3 + 1];
    const float wc = w1[o * 24 + i * 3 + 2];
#pragma unroll
    for (int j = 0; j < 8; ++j) accv[j] += wa * f[j] + wb * f[j + 1] + wc * f[j + 2];
  }
  float4* dst = (float4*)&q2[((size_t)b * CR + o) * NN + n0];
  dst[0] = make_float4(accv[0], accv[1], accv[2], accv[3]);
  dst[1] = make_float4(accv[4], accv[5], accv[6], accv[7]);
}

// ---------------------------------------------------------------------------
// conv1d 32->64ch, writes bf16 TRANSPOSED Qt[b][n][32] (pre-scaled by log2e),
// Kt[b][n][32]
__global__ __launch_bounds__(256) void k_adj2(const float* __restrict__ q2,
    const float* __restrict__ w2, const float* __restrict__ b2,
    unsigned short* __restrict__ Qt, unsigned short* __restrict__ Kt) {
  __shared__ float q2s[32][66];
  __shared__ float w2t[96][64];
  __shared__ float b2s[64];
  const int b = blockIdx.y, n0 = blockIdx.x * 64;
  const int t = threadIdx.x;
  for (int idx = t; idx < 32 * 66; idx += 256) {
    int c = idx / 66, nn = idx % 66;
    int n = n0 + nn - 1;
    q2s[c][nn] = (n >= 0 && n < NN) ? q2[((size_t)b * CR + c) * NN + n] : 0.f;
  }
  for (int idx = t; idx < 96 * 64; idx += 256) {
    int k = idx & 63, ct = idx >> 6;
    w2t[ct][k] = w2[k * 96 + ct];
  }
  if (t < 64) b2s[t] = b2[t];
  __syncthreads();
  const int nn = t & 63, kh = t >> 6;
  float acc[16];
#pragma unroll
  for (int i = 0; i < 16; ++i) acc[i] = b2s[kh * 16 + i];
  for (int c = 0; c < 32; ++c) {
    const float x0 = q2s[c][nn], x1 = q2s[c][nn + 1], x2 = q2s[c][nn + 2];
    const float* wa = &w2t[c * 3 + 0][kh * 16];
    const float* wb = &w2t[c * 3 + 1][kh * 16];
    const float* wc = &w2t[c * 3 + 2][kh * 16];
#pragma unroll
    for (int i = 0; i < 16; ++i)
      acc[i] += wa[i] * x0 + wb[i] * x1 + wc[i] * x2;
  }
  const size_t row = ((size_t)b * NN + n0 + nn) * 32;
  u16x8 qo, ko;
#pragma unroll
  for (int i = 0; i < 8; ++i) {
    qo[i] = f2b(acc[2 * i] * 1.44269504f);   // fold log2(e) into Q
    ko[i] = f2b(acc[2 * i + 1]);
  }
  *(u16x8*)(Qt + row + kh * 8) = qo;
  *(u16x8*)(Kt + row + kh * 8) = ko;
}

// ---------------------------------------------------------------------------
// Attention denominator producer: computes S for all 4 batches ONCE per (n,m),
// writes rden = rcp(sum_b exp2(S_b)) bf16 in consumer-tile-linear layout, and
// n-partial colsums psum[ntile][b][m].
// grid (128 ntile, 8 mseg), 512 thr = 8 waves (mt = w&3, nh = w>>2).
__global__ __launch_bounds__(512) void k_aden(const unsigned short* __restrict__ Qt,
    const unsigned short* __restrict__ Kt, unsigned short* __restrict__ rden,
    float* __restrict__ psum) {
  __shared__ float psl[2][4][512];   // 16 KB, each cell written exactly once
  const int ntile = blockIdx.x, mseg = blockIdx.y;
  const int t = threadIdx.x;
  const int w = t >> 6, l = t & 63;
  const int lo = l & 15, hi = l >> 4;
  const int mt = w & 3, nh = w >> 2;
  const f32x4 zero4 = (f32x4){0.f, 0.f, 0.f, 0.f};
  short8 qf[4];
#pragma unroll
  for (int bb = 0; bb < 4; ++bb)
    qf[bb] = *(const short8*)(Qt + ((size_t)(bb * NN + ntile * 32 + nh * 16 + lo)) * 32 + hi * 8);
  const int slot = (mt * 2 + nh) * 64 + hi * 16 + lo;   // 0..511
  for (int ch = 0; ch < 8; ++ch) {
    const int m0 = mseg * 512 + ch * 64;
    short8 kf[4];
#pragma unroll
    for (int bb = 0; bb < 4; ++bb)
      kf[bb] = *(const short8*)(Kt + ((size_t)(bb * NN + m0 + mt * 16 + lo)) * 32 + hi * 8);
    f32x4 s[4];
#pragma unroll
    for (int bb = 0; bb < 4; ++bb)
      s[bb] = __builtin_amdgcn_mfma_f32_16x16x32_bf16(kf[bb], qf[bb], zero4, 0, 0, 0);
    // lane holds (n = ntile*32 + nh*16 + lo, m = m0 + mt*16 + hi*4 + r)
    u16x4 av;
#pragma unroll
    for (int r = 0; r < 4; ++r) {
      float e[4];
#pragma unroll
      for (int bb = 0; bb < 4; ++bb)
        e[bb] = __builtin_amdgcn_exp2f(fminf(s[bb][r], 86.f));
      av[r] = f2b(__builtin_amdgcn_rcpf(e[0] + e[1] + e[2] + e[3]));
      // colsum partial over the 16 n in this lane group
#pragma unroll
      for (int bb = 0; bb < 4; ++bb) {
        float v = e[bb];
        v += __shfl_xor(v, 1, 64);
        v += __shfl_xor(v, 2, 64);
        v += __shfl_xor(v, 4, 64);
        v += __shfl_xor(v, 8, 64);
        if (lo == 0) psl[nh][bb][ch * 64 + mt * 16 + hi * 4 + r] = v;
      }
    }
    *(u16x4*)(rden + ((size_t)(ntile * 64 + mseg * 8 + ch)) * 2048 + slot * 4) = av;
  }
  __syncthreads();
  for (int idx = t; idx < 2048; idx += 512) {
    const int bb = idx >> 9, ml = idx & 511;
    psum[((size_t)(ntile * 4 + bb)) * NN + mseg * 512 + ml] = psl[0][bb][ml] + psl[1][bb][ml];
  }
}

// rcs[b][m] = 1 / sum_ntile psum[ntile][b][m]
__global__ void k_rsum(const float* __restrict__ psum, float* __restrict__ rcs) {
  const int gid = blockIdx.x * 256 + threadIdx.x;  // B*N = 16384
  const int b = gid >> 12, m = gid & (NN - 1);
  float S = 0.f;
  for (int nt = 0; nt < 128; ++nt) S += psum[((size_t)(nt * 4 + b)) * NN + m];
  rcs[gid] = 1.0f / S;
}

// ---------------------------------------------------------------------------
// Fused attention v15: batch-redundancy removed. Per chunk: 1 kf load,
// 1 S-MFMA (own batch), coalesced u16x4 rden read, 1 exp per element.
// Vs per-wave single-buffer write-late; As dbuf + 1 barrier/chunk.
__global__ __launch_bounds__(512, 6) void k_fused7(const unsigned short* __restrict__ Qt,
    const unsigned short* __restrict__ Kt, const unsigned short* __restrict__ Vb,
    const unsigned short* __restrict__ rden, const float* __restrict__ x,
    const float* __restrict__ rcs, const float* __restrict__ gamma,
    const float* __restrict__ spatial, unsigned short* __restrict__ fusb) {
  __shared__ unsigned short Pool[256 * 64 + 2 * 2304];  // Vs 32KB + As dbuf 9.2KB
  unsigned short* VsB = Pool;
  unsigned short* AsB = Pool + 256 * 64;
  const int id = blockIdx.x;
  const int b = (id & 7) >> 1;                   // batch pinned to XCD pair
  const int ntile = ((id >> 3) << 1) | (id & 1); // 0..127
  const int n0 = ntile * 32;
  const int t = threadIdx.x;
  const int w = t >> 6, l = t & 63;
  const int lo = l & 15, hi = l >> 4;
  const int mt = w & 3, ns = w >> 2;             // S role: 16m x 16n tile
  const f32x4 zero4 = (f32x4){0.f, 0.f, 0.f, 0.f};
  unsigned short* Vsw = VsB + w * 2048;          // per-wave 32c x 64m slice

  const short8 qf = *(const short8*)(Qt + ((size_t)(b * NN + n0 + ns * 16 + lo)) * 32 + hi * 8);

  f32x4 acc[2][2];
#pragma unroll
  for (int ct = 0; ct < 2; ++ct)
#pragma unroll
    for (int nt = 0; nt < 2; ++nt) acc[ct][nt] = zero4;

  const int cl_base = l >> 3, jj = l & 7;
  const unsigned short* vwave = Vb + ((size_t)(b * CC + w * 32)) * NN;
  const unsigned short* kbase = Kt + ((size_t)(b * NN + mt * 16 + lo)) * 32 + hi * 8;
  const unsigned short* rdbase = rden + ((size_t)ntile * 64) * 2048
                               + (size_t)((mt * 2 + ns) * 64 + hi * 16 + lo) * 4;
  const float* rcs_b = rcs + b * NN;
  const int as_off = (ns * 16 + lo) * 72 + mt * 16 + hi * 4;  // u16x4 slot

  // ---- prologue: chunk 0 -> Vs + As buf0; kf prefetched for chunk 1
  short8 kf = *(const short8*)(kbase);
  {
    u16x8 vst[4];
#pragma unroll
    for (int q = 0; q < 4; ++q) {
      const int cl = q * 8 + cl_base;
      vst[q] = *(const u16x8*)(vwave + (size_t)cl * NN + jj * 8);
    }
    const u16x4 rd4 = *(const u16x4*)(rdbase);
    const f32x4 s = __builtin_amdgcn_mfma_f32_16x16x32_bf16(kf, qf, zero4, 0, 0, 0);
    const f32x4 rc4 = *(const f32x4*)(rcs_b + mt * 16 + hi * 4);
    u16x4 av;
#pragma unroll
    for (int r = 0; r < 4; ++r) {
      const float e = __builtin_amdgcn_exp2f(fminf(s[r], 86.f));
      av[r] = f2b(e * (b2f(rd4[r]) + rc4[r]));
    }
    *(u16x4*)&AsB[as_off] = av;
#pragma unroll
    for (int q = 0; q < 4; ++q) {
      const int cl = q * 8 + cl_base;
      *(u16x8*)&Vsw[cl * 64 + ((jj ^ (cl & 7)) << 3)] = vst[q];
    }
    kf = *(const short8*)(kbase + (size_t)64 * 32);
  }
  __syncthreads();

  for (int ch = 0; ch < 64; ++ch) {
    const int cur = ch & 1;
    unsigned short* Asc = AsB + cur * 2304;
    unsigned short* Asn = AsB + (cur ^ 1) * 2304;
    u16x8 vst[4];
    u16x4 av;
    if (ch < 63) {
      const int m1 = (ch + 1) * 64;
#pragma unroll
      for (int q = 0; q < 4; ++q) {
        const int cl = q * 8 + cl_base;
        vst[q] = *(const u16x8*)(vwave + (size_t)cl * NN + m1 + jj * 8);
      }
      const u16x4 rd4 = *(const u16x4*)(rdbase + (size_t)(ch + 1) * 2048);
      const f32x4 s = __builtin_amdgcn_mfma_f32_16x16x32_bf16(kf, qf, zero4, 0, 0, 0);
      const f32x4 rc4 = *(const f32x4*)(rcs_b + m1 + mt * 16 + hi * 4);
#pragma unroll
      for (int r = 0; r < 4; ++r) {
        const float e = __builtin_amdgcn_exp2f(fminf(s[r], 86.f));
        av[r] = f2b(e * (b2f(rd4[r]) + rc4[r]));
      }
      const int m2 = (ch < 62) ? (m1 + 64) : m1;
      kf = *(const short8*)(kbase + (size_t)m2 * 32);
    }
    // ---- PV(ch): wave-private Vs + shared Asc
#pragma unroll
    for (int kt = 0; kt < 2; ++kt) {
      short8 af[2];
#pragma unroll
      for (int nt = 0; nt < 2; ++nt)
        af[nt] = *(const short8*)&Asc[(nt * 16 + lo) * 72 + kt * 32 + hi * 8];
#pragma unroll
      for (int ct = 0; ct < 2; ++ct) {
        const int cl = ct * 16 + lo;
        const short8 vf = *(const short8*)&Vsw[cl * 64 + (((kt * 4 + hi) ^ (cl & 7)) << 3)];
#pragma unroll
        for (int nt = 0; nt < 2; ++nt)
          acc[ct][nt] = __builtin_amdgcn_mfma_f32_16x16x32_bf16(vf, af[nt], acc[ct][nt], 0, 0, 0);
      }
    }
    // ---- write-late: next-chunk V (own slice) + As
    if (ch < 63) {
#pragma unroll
      for (int q = 0; q < 4; ++q) {
        const int cl = q * 8 + cl_base;
        *(u16x8*)&Vsw[cl * 64 + ((jj ^ (cl & 7)) << 3)] = vst[q];
      }
      *(u16x4*)&Asn[as_off] = av;
    }
    __syncthreads();
  }

  // ---- epilogue: gamma*mean*acc + x -> Fs (reuse pool) -> coalesced fusb
  unsigned short* Fs = Pool;
  const float g = gamma[0] * spatial[b];
#pragma unroll
  for (int ct = 0; ct < 2; ++ct) {
#pragma unroll
    for (int nt = 0; nt < 2; ++nt) {
      u16x4 o4;
#pragma unroll
      for (int r = 0; r < 4; ++r) {
        const int c = w * 32 + ct * 16 + hi * 4 + r;
        const float xv = x[((size_t)(b * CC + c)) * NN + n0 + nt * 16 + lo];
        o4[r] = f2b(g * acc[ct][nt][r] + xv);
      }
      *(u16x4*)&Fs[(nt * 16 + lo) * 264 + w * 32 + ct * 16 + hi * 4] = o4;
    }
  }
  __syncthreads();
  const int iy = n0 >> 6, ix0 = n0 & 63;
  unsigned short* fb = fusb + (((size_t)(b * 66 + iy + 1)) * 66 + ix0 + 1) * 256;
#pragma unroll
  for (int q = 0; q < 2; ++q) {
    const int u = t + q * 512;               // 0..1023
    const int nl = u >> 5, c0 = (u & 31) * 8;
    *(u16x8*)(fb + (size_t)nl * 256 + c0) = *(const u16x8*)&Fs[nl * 264 + c0];
  }
}

// ---------------------------------------------------------------------------
// weight transform: wbf[p][tap][o][ic] (bf16, ic contiguous)
__global__ void k_wprep(const float* __restrict__ w_co, unsigned short* __restrict__ wbf) {
  const int gid = blockIdx.x * 256 + threadIdx.x;
  const int ic = gid & 255;
  const int o = (gid >> 8) & 127;
  const int tap = (gid >> 15) & 3;
  const int p = gid >> 17;
  const int py = p >> 1, px = p & 1;
  const int tyi = tap >> 1, txi = tap & 1;
  const int ky = py + 2 * tyi, kx = px + 2 * txi;
  wbf[gid] = f2b(w_co[(ic * 128 + o) * 16 + (3 - ky) * 4 + (3 - kx)]);
}

// ---------------------------------------------------------------------------
// MFMA transposed conv v3: LDS-staged F rows + weight panels per 32-ic chunk.
__global__ __launch_bounds__(512) void k_deconv(const unsigned short* __restrict__ fusb,
    const unsigned short* __restrict__ wbf, const float* __restrict__ b_co,
    float* __restrict__ out) {
  __shared__ unsigned short Fsh[5 * 66 * 36];    // 23.8 KB
  __shared__ unsigned short Wsh[4 * 128 * 36];   // 36.9 KB
  const int bp = blockIdx.y;
  const int b = bp >> 2, py = (bp >> 1) & 1, px = bp & 1;
  const int t = threadIdx.x;
  const int w = t >> 6, l = t & 63;
  const int lo = l & 15, hi = l >> 4;
  const int wm = w & 1, wrow = w >> 1;
  const int iy0 = blockIdx.x * 4;
  const int iy = iy0 + wrow;
  f32x4 acc[4][4];
#pragma unroll
  for (int mt = 0; mt < 4; ++mt)
#pragma unroll
    for (int nt = 0; nt < 4; ++nt) acc[mt][nt] = (f32x4){0.f, 0.f, 0.f, 0.f};
  const unsigned short* wp_base = wbf + (size_t)(bp & 3) * 4 * 128 * 256;
  const size_t frow0 = (size_t)(b * 66 + iy0 + py) * 66;

  for (int ic0 = 0; ic0 < 256; ic0 += 32) {
    __syncthreads();
#pragma unroll
    for (int pass = 0; pass < 3; ++pass) {
      const int idx = t + pass * 512;
      if (idx < 1320) {
        const int rr = idx / 264, rem = idx % 264;
        const int xxp = rem >> 2, h = rem & 3;
        const u16x8 v = *(const u16x8*)(fusb + (frow0 + (size_t)rr * 66 + xxp) * 256 + ic0 + h * 8);
        *(u16x8*)&Fsh[(rr * 66 + xxp) * 36 + h * 8] = v;
      }
    }
#pragma unroll
    for (int pass = 0; pass < 4; ++pass) {
      const int idx = t + pass * 512;
      const int tap = idx >> 9, o = (idx >> 2) & 127, h = idx & 3;
      const u16x8 v = *(const u16x8*)(wp_base + (size_t)tap * 32768 + (size_t)o * 256 + ic0 + h * 8);
      *(u16x8*)&Wsh[(tap * 128 + o) * 36 + h * 8] = v;
    }
    __syncthreads();
#pragma unroll
    for (int tap = 0; tap < 4; ++tap) {
      const int tyi = tap >> 1, txi = tap & 1;
      const int dx = px + txi - 1;
      const int rr = wrow + tyi;
      short8 a[4], bf[4];
#pragma unroll
      for (int mt = 0; mt < 4; ++mt)
        a[mt] = *(const short8*)&Wsh[(tap * 128 + wm * 64 + mt * 16 + lo) * 36 + hi * 8];
#pragma unroll
      for (int nt = 0; nt < 4; ++nt)
        bf[nt] = *(const short8*)&Fsh[(rr * 66 + nt * 16 + lo + dx + 1) * 36 + hi * 8];
#pragma unroll
      for (int mt = 0; mt < 4; ++mt)
#pragma unroll
        for (int nt = 0; nt < 4; ++nt)
          acc[mt][nt] = __builtin_amdgcn_mfma_f32_16x16x32_bf16(a[mt], bf[nt], acc[mt][nt], 0, 0, 0);
    }
  }
  const int y = 2 * iy + py;
#pragma unroll
  for (int mt = 0; mt < 4; ++mt) {
#pragma unroll
    for (int nt = 0; nt < 4; ++nt) {
#pragma unroll
      for (int r = 0; r < 4; ++r) {
        const int o = wm * 64 + mt * 16 + hi * 4 + r;
        const int xx = 2 * (nt * 16 + lo) + px;
        out[(((size_t)(b * OCH + o)) * 128 + y) * 128 + xx] = acc[mt][nt][r] + b_co[o];
      }
    }
  }
}

// ---------------------------------------------------------------------------
extern "C" void kernel_launch(void* const* d_in, const int* in_sizes, int n_in,
                              void* d_out, int out_size, void* d_ws, size_t ws_size,
                              hipStream_t stream) {
  const float* x     = (const float*)d_in[0];
  const float* wq    = (const float*)d_in[1];
  const float* bq    = (const float*)d_in[2];
  const float* wv    = (const float*)d_in[3];
  const float* bv    = (const float*)d_in[4];
  const float* w1    = (const float*)d_in[5];
  const float* b1    = (const float*)d_in[6];
  const float* w2    = (const float*)d_in[7];
  const float* b2    = (const float*)d_in[8];
  const float* gamma = (const float*)d_in[9];
  const float* w_co  = (const float*)d_in[10];
  const float* b_co  = (const float*)d_in[11];
  float* out = (float*)d_out;
  (void)in_sizes; (void)n_in; (void)out_size; (void)ws_size;

  char* p = (char*)d_ws;
  unsigned short* xt      = (unsigned short*)p; p += (size_t)BN * NN * CC * 2;      // 8.4 MB
  unsigned short* q1b     = (unsigned short*)p; p += (size_t)BN * CC * NN * 2;      // 8.4 MB
  float*          q2      = (float*)p;          p += (size_t)BN * CR * NN * 4;      // 2 MB
  float*          part2   = (float*)p;          p += (size_t)1024 * 4;
  unsigned short* Qt      = (unsigned short*)p; p += (size_t)BN * NN * 32 * 2;      // 1 MB
  unsigned short* Kt      = (unsigned short*)p; p += (size_t)BN * NN * 32 * 2;      // 1 MB
  unsigned short* Vb      = (unsigned short*)p; p += (size_t)BN * CC * NN * 2;      // 8.4 MB
  float*          rcs     = (float*)p;          p += (size_t)BN * NN * 4;
  float*          spatial = (float*)p;          p += 256;
  unsigned short* wqb     = (unsigned short*)p; p += (size_t)CC * CC * 2;
  unsigned short* wvb     = (unsigned short*)p; p += (size_t)CC * CC * 2;
  unsigned short* wbf     = (unsigned short*)p; p += (size_t)4 * 4 * 128 * 256 * 2; // 1 MB
  unsigned short* fusb    = (unsigned short*)p; p += (size_t)BN * 66 * 66 * 256 * 2;// 8.9 MB
  unsigned short* rden    = (unsigned short*)p; p += (size_t)NN * NN * 2;           // 33.5 MB
  float*          psum    = (float*)xt;         // overlay: xt dead after k_projm

  // border-zero padded fusion buffer
  hipMemsetAsync(fusb, 0, (size_t)BN * 66 * 66 * 256 * 2, stream);

  k_wcast<<<dim3(64, 2), 256, 0, stream>>>(wq, wv, wqb, wvb);
  k_xt<<<dim3(64, 4, 4), 256, 0, stream>>>(x, xt, part2);
  k_projm<<<dim3(128, 4, 2), 256, 0, stream>>>(xt, wqb, bq, wvb, bv, q1b, Vb);
  k_adj1<<<dim3(256), 256, 0, stream>>>(q1b, w1, b1, q2);
  k_adj2<<<dim3(64, 4), 256, 0, stream>>>(q2, w2, b2, Qt, Kt);
  k_spatial2<<<dim3(4), 256, 0, stream>>>(part2, spatial);
  k_aden<<<dim3(128, 8), 512, 0, stream>>>(Qt, Kt, rden, psum);
  k_rsum<<<dim3(64), 256, 0, stream>>>(psum, rcs);
  k_wprep<<<dim3(2048), 256, 0, stream>>>(w_co, wbf);
  k_fused7<<<dim3(512), 512, 0, stream>>>(Qt, Kt, Vb, rden, x, rcs, gamma, spatial, fusb);
  k_deconv<<<dim3(16, 16), 512, 0, stream>>>(fusb, wbf, b_co, out);
}

// Round 17
// 219.011 us; speedup vs baseline: 1.1069x; 1.1069x over previous
//
#include <hip/hip_runtime.h>

#define BN 4
#define CC 256
#define NN 4096
#define CR 32
#define OCH 128
#define SEGS 8

typedef float f32x4 __attribute__((ext_vector_type(4)));
typedef short short8 __attribute__((ext_vector_type(8)));
typedef unsigned short u16x8 __attribute__((ext_vector_type(8)));
typedef unsigned short u16x4 __attribute__((ext_vector_type(4)));

__device__ __forceinline__ unsigned short f2b(float f) {
  unsigned u = __builtin_bit_cast(unsigned, f);
  u += 0x7fff + ((u >> 16) & 1);
  return (unsigned short)(u >> 16);
}
__device__ __forceinline__ float b2f(unsigned short h) {
  unsigned u = ((unsigned)h) << 16;
  return __builtin_bit_cast(float, u);
}

// ---------------------------------------------------------------------------
// cast wq / wv to bf16
__global__ __launch_bounds__(256) void k_wcast(const float* __restrict__ wq,
    const float* __restrict__ wv, unsigned short* __restrict__ wqb,
    unsigned short* __restrict__ wvb) {
  const int gid = (blockIdx.x * 256 + threadIdx.x) * 4;
  const float* src = blockIdx.y ? wv : wq;
  unsigned short* dst = blockIdx.y ? wvb : wqb;
  const float4 v = *(const float4*)(src + gid);
  u16x4 o; o[0] = f2b(v.x); o[1] = f2b(v.y); o[2] = f2b(v.z); o[3] = f2b(v.w);
  *(u16x4*)(dst + gid) = o;
}

// ---------------------------------------------------------------------------
// transpose+cast x[b][c][n] f32 -> xt[b][n][c] bf16, fused partial spatial sum
__global__ __launch_bounds__(256) void k_xt(const float* __restrict__ x,
    unsigned short* __restrict__ xt, float* __restrict__ part2) {
  __shared__ unsigned short T[64][65];
  __shared__ float red[256];
  const int b = blockIdx.z, c0 = blockIdx.y * 64, n0 = blockIdx.x * 64;
  const int t = threadIdx.x;
  float s = 0.f;
  for (int idx = t; idx < 4096; idx += 256) {
    int i = idx >> 6, j = idx & 63;
    const float v = x[((size_t)(b * CC + c0 + i)) * NN + n0 + j];
    s += v;
    T[i][j] = f2b(v);
  }
  __syncthreads();
  for (int idx = t; idx < 4096; idx += 256) {
    int j = idx >> 6, i = idx & 63;
    xt[((size_t)(b * NN + n0 + j)) * CC + c0 + i] = T[i][j];
  }
  red[t] = s;
  __syncthreads();
  for (int d = 128; d > 0; d >>= 1) {
    if (t < d) red[t] += red[t + d];
    __syncthreads();
  }
  if (t == 0) part2[b * 256 + blockIdx.y * 64 + blockIdx.x] = red[0];
}

__global__ void k_spatial2(const float* __restrict__ part2, float* __restrict__ spatial) {
  const int b = blockIdx.x;
  const int t = threadIdx.x;
  __shared__ float red[256];
  red[t] = part2[b * 256 + t];
  __syncthreads();
  for (int d = 128; d > 0; d >>= 1) {
    if (t < d) red[t] += red[t + d];
    __syncthreads();
  }
  if (t == 0) spatial[b] = red[0] * (1.0f / ((float)CC * NN));
}

// ---------------------------------------------------------------------------
// MFMA projection GEMM: out[b][c][n] = bias[c] + sum_j W[c][j] xt[b][n][j]
__global__ __launch_bounds__(256) void k_projm(const unsigned short* __restrict__ xt,
    const unsigned short* __restrict__ wqb, const float* __restrict__ bq,
    const unsigned short* __restrict__ wvb, const float* __restrict__ bv,
    unsigned short* __restrict__ q1b, unsigned short* __restrict__ Vb) {
  const int b = blockIdx.y, n0 = blockIdx.x * 32, which = blockIdx.z;
  const unsigned short* W = which ? wvb : wqb;
  const float* bias = which ? bv : bq;
  unsigned short* out = which ? Vb : q1b;
  const int t = threadIdx.x;
  const int w = t >> 6, l = t & 63;
  const int lo = l & 15, hi = l >> 4;
  const int oc0 = w * 64;
  f32x4 acc[4][2];
#pragma unroll
  for (int ct = 0; ct < 4; ++ct)
#pragma unroll
    for (int nt = 0; nt < 2; ++nt) acc[ct][nt] = (f32x4){0.f, 0.f, 0.f, 0.f};
  const unsigned short* wb = W + (size_t)(oc0 + lo) * CC + hi * 8;
  const unsigned short* xb = xt + ((size_t)(b * NN + n0 + lo)) * CC + hi * 8;
#pragma unroll
  for (int k0 = 0; k0 < CC; k0 += 32) {
    short8 aw[4], bx[2];
#pragma unroll
    for (int ct = 0; ct < 4; ++ct) aw[ct] = *(const short8*)(wb + ct * 16 * CC + k0);
#pragma unroll
    for (int nt = 0; nt < 2; ++nt) bx[nt] = *(const short8*)(xb + nt * 16 * CC + k0);
#pragma unroll
    for (int ct = 0; ct < 4; ++ct)
#pragma unroll
      for (int nt = 0; nt < 2; ++nt)
        acc[ct][nt] = __builtin_amdgcn_mfma_f32_16x16x32_bf16(aw[ct], bx[nt], acc[ct][nt], 0, 0, 0);
  }
#pragma unroll
  for (int ct = 0; ct < 4; ++ct) {
#pragma unroll
    for (int r = 0; r < 4; ++r) {
      const int c = oc0 + ct * 16 + hi * 4 + r;
      const float bvv = bias[c];
#pragma unroll
      for (int nt = 0; nt < 2; ++nt)
        out[((size_t)(b * CC + c)) * NN + n0 + nt * 16 + lo] = f2b(acc[ct][nt][r] + bvv);
    }
  }
}

// ---------------------------------------------------------------------------
// grouped conv1d (bf16 in, f32 out), vectorized: thread = 8 consecutive n
__global__ __launch_bounds__(256) void k_adj1(const unsigned short* __restrict__ q1,
    const float* __restrict__ w1, const float* __restrict__ b1,
    float* __restrict__ q2) {
  const int gid = blockIdx.x * 256 + threadIdx.x;   // B*32*(N/8) = 65536
  const int n8 = gid & 511;
  const int o = (gid >> 9) & 31;
  const int b = gid >> 14;
  const int n0 = n8 * 8;
  const unsigned short* base = q1 + ((size_t)b * CC + o * 8) * NN;
  float accv[8];
  const float bias = b1[o];
#pragma unroll
  for (int j = 0; j < 8; ++j) accv[j] = bias;
#pragma unroll
  for (int i = 0; i < 8; ++i) {
    const unsigned short* r = base + (size_t)i * NN;
    const u16x8 v = *(const u16x8*)(r + n0);
    float f[10];
    f[0] = (n0 > 0) ? b2f(r[n0 - 1]) : 0.f;
#pragma unroll
    for (int j = 0; j < 8; ++j) f[j + 1] = b2f(v[j]);
    f[9] = (n0 + 8 < NN) ? b2f(r[n0 + 8]) : 0.f;
    const float wa = w1[o * 24 + i * 3 + 0];
    const float wb = w1[o * 24 + i * 3 + 1];
    const float wc = w1[o * 24 + i * 3 + 2];
#pragma unroll
    for (int j = 0; j < 8; ++j) accv[j] += wa * f[j] + wb * f[j + 1] + wc * f[j + 2];
  }
  float4* dst = (float4*)&q2[((size_t)b * CR + o) * NN + n0];
  dst[0] = make_float4(accv[0], accv[1], accv[2], accv[3]);
  dst[1] = make_float4(accv[4], accv[5], accv[6], accv[7]);
}

// ---------------------------------------------------------------------------
// conv1d 32->64ch, writes bf16 TRANSPOSED Qt[b][n][32] (pre-scaled by log2e),
// Kt[b][n][32]
__global__ __launch_bounds__(256) void k_adj2(const float* __restrict__ q2,
    const float* __restrict__ w2, const float* __restrict__ b2,
    unsigned short* __restrict__ Qt, unsigned short* __restrict__ Kt) {
  __shared__ float q2s[32][66];
  __shared__ float w2t[96][64];
  __shared__ float b2s[64];
  const int b = blockIdx.y, n0 = blockIdx.x * 64;
  const int t = threadIdx.x;
  for (int idx = t; idx < 32 * 66; idx += 256) {
    int c = idx / 66, nn = idx % 66;
    int n = n0 + nn - 1;
    q2s[c][nn] = (n >= 0 && n < NN) ? q2[((size_t)b * CR + c) * NN + n] : 0.f;
  }
  for (int idx = t; idx < 96 * 64; idx += 256) {
    int k = idx & 63, ct = idx >> 6;
    w2t[ct][k] = w2[k * 96 + ct];
  }
  if (t < 64) b2s[t] = b2[t];
  __syncthreads();
  const int nn = t & 63, kh = t >> 6;
  float acc[16];
#pragma unroll
  for (int i = 0; i < 16; ++i) acc[i] = b2s[kh * 16 + i];
  for (int c = 0; c < 32; ++c) {
    const float x0 = q2s[c][nn], x1 = q2s[c][nn + 1], x2 = q2s[c][nn + 2];
    const float* wa = &w2t[c * 3 + 0][kh * 16];
    const float* wb = &w2t[c * 3 + 1][kh * 16];
    const float* wc = &w2t[c * 3 + 2][kh * 16];
#pragma unroll
    for (int i = 0; i < 16; ++i)
      acc[i] += wa[i] * x0 + wb[i] * x1 + wc[i] * x2;
  }
  const size_t row = ((size_t)b * NN + n0 + nn) * 32;
  u16x8 qo, ko;
#pragma unroll
  for (int i = 0; i < 8; ++i) {
    qo[i] = f2b(acc[2 * i] * 1.44269504f);   // fold log2(e) into Q
    ko[i] = f2b(acc[2 * i + 1]);
  }
  *(u16x8*)(Qt + row + kh * 8) = qo;
  *(u16x8*)(Kt + row + kh * 8) = ko;
}

// ---------------------------------------------------------------------------
// MFMA column exp-sum (round-15 version: register-accumulated, 2 shfl at end)
// psum[b][seg][m] = sum_{n in seg} exp2(S'[b][n][m])
__global__ __launch_bounds__(512) void k_colstatm(const unsigned short* __restrict__ Qt,
    const unsigned short* __restrict__ Kt, float* __restrict__ psum) {
  __shared__ float CS[2][4][64];
  const int m0 = blockIdx.x * 64, seg = blockIdx.y;
  const int t = threadIdx.x;
  const int w = t >> 6, l = t & 63;
  const int lo = l & 15, hi = l >> 4;
  const int mt = w & 3, nt2 = w >> 2;
  const f32x4 zero4 = (f32x4){0.f, 0.f, 0.f, 0.f};
  short8 kf[4];
#pragma unroll
  for (int bb = 0; bb < 4; ++bb)
    kf[bb] = *(const short8*)(Kt + ((size_t)(bb * NN + m0 + mt * 16 + lo)) * 32 + hi * 8);
  float colacc[4] = {0.f, 0.f, 0.f, 0.f};
  for (int ch = 0; ch < 8; ++ch) {
    const int nb = seg * 512 + ch * 64;
    short8 qf[2][4];
#pragma unroll
    for (int pos = 0; pos < 2; ++pos)
#pragma unroll
      for (int bb = 0; bb < 4; ++bb)
        qf[pos][bb] = *(const short8*)(Qt + ((size_t)(bb * NN + nb + (nt2 * 2 + pos) * 16 + lo)) * 32 + hi * 8);
#pragma unroll
    for (int pos = 0; pos < 2; ++pos) {
#pragma unroll
      for (int bb = 0; bb < 4; ++bb) {
        const f32x4 s = __builtin_amdgcn_mfma_f32_16x16x32_bf16(qf[pos][bb], kf[bb], zero4, 0, 0, 0);
#pragma unroll
        for (int r = 0; r < 4; ++r) colacc[bb] += __builtin_amdgcn_exp2f(fminf(s[r], 86.f));
      }
    }
  }
#pragma unroll
  for (int bb = 0; bb < 4; ++bb) {
    colacc[bb] += __shfl_xor(colacc[bb], 16, 64);
    colacc[bb] += __shfl_xor(colacc[bb], 32, 64);
  }
  if (hi == 0) {
#pragma unroll
    for (int bb = 0; bb < 4; ++bb) CS[nt2][bb][mt * 16 + lo] = colacc[bb];
  }
  __syncthreads();
  if (t < 256) {
    const int bb = t >> 6, mm = t & 63;
    psum[((size_t)(bb * SEGS + seg)) * NN + m0 + mm] = CS[0][bb][mm] + CS[1][bb][mm];
  }
}

__global__ void k_rsum(const float* __restrict__ psum, float* __restrict__ rcs) {
  const int gid = blockIdx.x * 256 + threadIdx.x;  // B*N = 16384
  const int b = gid >> 12, m = gid & (NN - 1);
  float S = 0.f;
#pragma unroll
  for (int s = 0; s < SEGS; ++s) S += psum[((size_t)(b * SEGS + s)) * NN + m];
  rcs[gid] = 1.0f / S;
}

// ---------------------------------------------------------------------------
// rden producer (slim): rden = rcp(sum_b exp2(S_b)) bf16, consumer-tile layout.
// No colsum work here (k_colstatm handles it). Coalesced u16x4 stores.
// grid (128 ntile, 8 mseg), 512 thr = 8 waves (mt = w&3, nh = w>>2).
__global__ __launch_bounds__(512) void k_aden(const unsigned short* __restrict__ Qt,
    const unsigned short* __restrict__ Kt, unsigned short* __restrict__ rden) {
  const int ntile = blockIdx.x, mseg = blockIdx.y;
  const int t = threadIdx.x;
  const int w = t >> 6, l = t & 63;
  const int lo = l & 15, hi = l >> 4;
  const int mt = w & 3, nh = w >> 2;
  const f32x4 zero4 = (f32x4){0.f, 0.f, 0.f, 0.f};
  short8 qf[4];
#pragma unroll
  for (int bb = 0; bb < 4; ++bb)
    qf[bb] = *(const short8*)(Qt + ((size_t)(bb * NN + ntile * 32 + nh * 16 + lo)) * 32 + hi * 8);
  const int slot = (mt * 2 + nh) * 64 + hi * 16 + lo;   // 0..511
  for (int ch = 0; ch < 8; ++ch) {
    const int m0 = mseg * 512 + ch * 64;
    short8 kf[4];
#pragma unroll
    for (int bb = 0; bb < 4; ++bb)
      kf[bb] = *(const short8*)(Kt + ((size_t)(bb * NN + m0 + mt * 16 + lo)) * 32 + hi * 8);
    f32x4 s[4];
#pragma unroll
    for (int bb = 0; bb < 4; ++bb)
      s[bb] = __builtin_amdgcn_mfma_f32_16x16x32_bf16(kf[bb], qf[bb], zero4, 0, 0, 0);
    // lane holds (n = ntile*32 + nh*16 + lo, m = m0 + mt*16 + hi*4 + r)
    u16x4 av;
#pragma unroll
    for (int r = 0; r < 4; ++r) {
      const float e0 = __builtin_amdgcn_exp2f(fminf(s[0][r], 86.f));
      const float e1 = __builtin_amdgcn_exp2f(fminf(s[1][r], 86.f));
      const float e2 = __builtin_amdgcn_exp2f(fminf(s[2][r], 86.f));
      const float e3 = __builtin_amdgcn_exp2f(fminf(s[3][r], 86.f));
      av[r] = f2b(__builtin_amdgcn_rcpf(e0 + e1 + e2 + e3));
    }
    *(u16x4*)(rden + ((size_t)(ntile * 64 + mseg * 8 + ch)) * 2048 + slot * 4) = av;
  }
}

// ---------------------------------------------------------------------------
// Fused attention v15: batch-redundancy removed. Per chunk: 1 kf load,
// 1 S-MFMA (own batch), coalesced u16x4 rden read, 1 exp per element.
// Vs per-wave single-buffer write-late; As dbuf + 1 barrier/chunk.
__global__ __launch_bounds__(512, 6) void k_fused7(const unsigned short* __restrict__ Qt,
    const unsigned short* __restrict__ Kt, const unsigned short* __restrict__ Vb,
    const unsigned short* __restrict__ rden, const float* __restrict__ x,
    const float* __restrict__ rcs, const float* __restrict__ gamma,
    const float* __restrict__ spatial, unsigned short* __restrict__ fusb) {
  __shared__ unsigned short Pool[256 * 64 + 2 * 2304];  // Vs 32KB + As dbuf 9.2KB
  unsigned short* VsB = Pool;
  unsigned short* AsB = Pool + 256 * 64;
  const int id = blockIdx.x;
  const int b = (id & 7) >> 1;                   // batch pinned to XCD pair
  const int ntile = ((id >> 3) << 1) | (id & 1); // 0..127
  const int n0 = ntile * 32;
  const int t = threadIdx.x;
  const int w = t >> 6, l = t & 63;
  const int lo = l & 15, hi = l >> 4;
  const int mt = w & 3, ns = w >> 2;             // S role: 16m x 16n tile
  const f32x4 zero4 = (f32x4){0.f, 0.f, 0.f, 0.f};
  unsigned short* Vsw = VsB + w * 2048;          // per-wave 32c x 64m slice

  const short8 qf = *(const short8*)(Qt + ((size_t)(b * NN + n0 + ns * 16 + lo)) * 32 + hi * 8);

  f32x4 acc[2][2];
#pragma unroll
  for (int ct = 0; ct < 2; ++ct)
#pragma unroll
    for (int nt = 0; nt < 2; ++nt) acc[ct][nt] = zero4;

  const int cl_base = l >> 3, jj = l & 7;
  const unsigned short* vwave = Vb + ((size_t)(b * CC + w * 32)) * NN;
  const unsigned short* kbase = Kt + ((size_t)(b * NN + mt * 16 + lo)) * 32 + hi * 8;
  const unsigned short* rdbase = rden + ((size_t)ntile * 64) * 2048
                               + (size_t)((mt * 2 + ns) * 64 + hi * 16 + lo) * 4;
  const float* rcs_b = rcs + b * NN;
  const int as_off = (ns * 16 + lo) * 72 + mt * 16 + hi * 4;  // u16x4 slot

  // ---- prologue: chunk 0 -> Vs + As buf0; kf prefetched for chunk 1
  short8 kf = *(const short8*)(kbase);
  {
    u16x8 vst[4];
#pragma unroll
    for (int q = 0; q < 4; ++q) {
      const int cl = q * 8 + cl_base;
      vst[q] = *(const u16x8*)(vwave + (size_t)cl * NN + jj * 8);
    }
    const u16x4 rd4 = *(const u16x4*)(rdbase);
    const f32x4 s = __builtin_amdgcn_mfma_f32_16x16x32_bf16(kf, qf, zero4, 0, 0, 0);
    const f32x4 rc4 = *(const f32x4*)(rcs_b + mt * 16 + hi * 4);
    u16x4 av;
#pragma unroll
    for (int r = 0; r < 4; ++r) {
      const float e = __builtin_amdgcn_exp2f(fminf(s[r], 86.f));
      av[r] = f2b(e * (b2f(rd4[r]) + rc4[r]));
    }
    *(u16x4*)&AsB[as_off] = av;
#pragma unroll
    for (int q = 0; q < 4; ++q) {
      const int cl = q * 8 + cl_base;
      *(u16x8*)&Vsw[cl * 64 + ((jj ^ (cl & 7)) << 3)] = vst[q];
    }
    kf = *(const short8*)(kbase + (size_t)64 * 32);
  }
  __syncthreads();

  for (int ch = 0; ch < 64; ++ch) {
    const int cur = ch & 1;
    unsigned short* Asc = AsB + cur * 2304;
    unsigned short* Asn = AsB + (cur ^ 1) * 2304;
    u16x8 vst[4];
    u16x4 av;
    if (ch < 63) {
      const int m1 = (ch + 1) * 64;
#pragma unroll
      for (int q = 0; q < 4; ++q) {
        const int cl = q * 8 + cl_base;
        vst[q] = *(const u16x8*)(vwave + (size_t)cl * NN + m1 + jj * 8);
      }
      const u16x4 rd4 = *(const u16x4*)(rdbase + (size_t)(ch + 1) * 2048);
      const f32x4 s = __builtin_amdgcn_mfma_f32_16x16x32_bf16(kf, qf, zero4, 0, 0, 0);
      const f32x4 rc4 = *(const f32x4*)(rcs_b + m1 + mt * 16 + hi * 4);
#pragma unroll
      for (int r = 0; r < 4; ++r) {
        const float e = __builtin_amdgcn_exp2f(fminf(s[r], 86.f));
        av[r] = f2b(e * (b2f(rd4[r]) + rc4[r]));
      }
      const int m2 = (ch < 62) ? (m1 + 64) : m1;
      kf = *(const short8*)(kbase + (size_t)m2 * 32);
    }
    // ---- PV(ch): wave-private Vs + shared Asc
#pragma unroll
    for (int kt = 0; kt < 2; ++kt) {
      short8 af[2];
#pragma unroll
      for (int nt = 0; nt < 2; ++nt)
        af[nt] = *(const short8*)&Asc[(nt * 16 + lo) * 72 + kt * 32 + hi * 8];
#pragma unroll
      for (int ct = 0; ct < 2; ++ct) {
        const int cl = ct * 16 + lo;
        const short8 vf = *(const short8*)&Vsw[cl * 64 + (((kt * 4 + hi) ^ (cl & 7)) << 3)];
#pragma unroll
        for (int nt = 0; nt < 2; ++nt)
          acc[ct][nt] = __builtin_amdgcn_mfma_f32_16x16x32_bf16(vf, af[nt], acc[ct][nt], 0, 0, 0);
      }
    }
    // ---- write-late: next-chunk V (own slice) + As
    if (ch < 63) {
#pragma unroll
      for (int q = 0; q < 4; ++q) {
        const int cl = q * 8 + cl_base;
        *(u16x8*)&Vsw[cl * 64 + ((jj ^ (cl & 7)) << 3)] = vst[q];
      }
      *(u16x4*)&Asn[as_off] = av;
    }
    __syncthreads();
  }

  // ---- epilogue: gamma*mean*acc + x -> Fs (reuse pool) -> coalesced fusb
  unsigned short* Fs = Pool;
  const float g = gamma[0] * spatial[b];
#pragma unroll
  for (int ct = 0; ct < 2; ++ct) {
#pragma unroll
    for (int nt = 0; nt < 2; ++nt) {
      u16x4 o4;
#pragma unroll
      for (int r = 0; r < 4; ++r) {
        const int c = w * 32 + ct * 16 + hi * 4 + r;
        const float xv = x[((size_t)(b * CC + c)) * NN + n0 + nt * 16 + lo];
        o4[r] = f2b(g * acc[ct][nt][r] + xv);
      }
      *(u16x4*)&Fs[(nt * 16 + lo) * 264 + w * 32 + ct * 16 + hi * 4] = o4;
    }
  }
  __syncthreads();
  const int iy = n0 >> 6, ix0 = n0 & 63;
  unsigned short* fb = fusb + (((size_t)(b * 66 + iy + 1)) * 66 + ix0 + 1) * 256;
#pragma unroll
  for (int q = 0; q < 2; ++q) {
    const int u = t + q * 512;               // 0..1023
    const int nl = u >> 5, c0 = (u & 31) * 8;
    *(u16x8*)(fb + (size_t)nl * 256 + c0) = *(const u16x8*)&Fs[nl * 264 + c0];
  }
}

// ---------------------------------------------------------------------------
// weight transform: wbf[p][tap][o][ic] (bf16, ic contiguous)
__global__ void k_wprep(const float* __restrict__ w_co, unsigned short* __restrict__ wbf) {
  const int gid = blockIdx.x * 256 + threadIdx.x;
  const int ic = gid & 255;
  const int o = (gid >> 8) & 127;
  const int tap = (gid >> 15) & 3;
  const int p = gid >> 17;
  const int py = p >> 1, px = p & 1;
  const int tyi = tap >> 1, txi = tap & 1;
  const int ky = py + 2 * tyi, kx = px + 2 * txi;
  wbf[gid] = f2b(w_co[(ic * 128 + o) * 16 + (3 - ky) * 4 + (3 - kx)]);
}

// ---------------------------------------------------------------------------
// MFMA transposed conv v3: LDS-staged F rows + weight panels per 32-ic chunk.
__global__ __launch_bounds__(512) void k_deconv(const unsigned short* __restrict__ fusb,
    const unsigned short* __restrict__ wbf, const float* __restrict__ b_co,
    float* __restrict__ out) {
  __shared__ unsigned short Fsh[5 * 66 * 36];    // 23.8 KB
  __shared__ unsigned short Wsh[4 * 128 * 36];   // 36.9 KB
  const int bp = blockIdx.y;
  const int b = bp >> 2, py = (bp >> 1) & 1, px = bp & 1;
  const int t = threadIdx.x;
  const int w = t >> 6, l = t & 63;
  const int lo = l & 15, hi = l >> 4;
  const int wm = w & 1, wrow = w >> 1;
  const int iy0 = blockIdx.x * 4;
  const int iy = iy0 + wrow;
  f32x4 acc[4][4];
#pragma unroll
  for (int mt = 0; mt < 4; ++mt)
#pragma unroll
    for (int nt = 0; nt < 4; ++nt) acc[mt][nt] = (f32x4){0.f, 0.f, 0.f, 0.f};
  const unsigned short* wp_base = wbf + (size_t)(bp & 3) * 4 * 128 * 256;
  const size_t frow0 = (size_t)(b * 66 + iy0 + py) * 66;

  for (int ic0 = 0; ic0 < 256; ic0 += 32) {
    __syncthreads();
#pragma unroll
    for (int pass = 0; pass < 3; ++pass) {
      const int idx = t + pass * 512;
      if (idx < 1320) {
        const int rr = idx / 264, rem = idx % 264;
        const int xxp = rem >> 2, h = rem & 3;
        const u16x8 v = *(const u16x8*)(fusb + (frow0 + (size_t)rr * 66 + xxp) * 256 + ic0 + h * 8);
        *(u16x8*)&Fsh[(rr * 66 + xxp) * 36 + h * 8] = v;
      }
    }
#pragma unroll
    for (int pass = 0; pass < 4; ++pass) {
      const int idx = t + pass * 512;
      const int tap = idx >> 9, o = (idx >> 2) & 127, h = idx & 3;
      const u16x8 v = *(const u16x8*)(wp_base + (size_t)tap * 32768 + (size_t)o * 256 + ic0 + h * 8);
      *(u16x8*)&Wsh[(tap * 128 + o) * 36 + h * 8] = v;
    }
    __syncthreads();
#pragma unroll
    for (int tap = 0; tap < 4; ++tap) {
      const int tyi = tap >> 1, txi = tap & 1;
      const int dx = px + txi - 1;
      const int rr = wrow + tyi;
      short8 a[4], bf[4];
#pragma unroll
      for (int mt = 0; mt < 4; ++mt)
        a[mt] = *(const short8*)&Wsh[(tap * 128 + wm * 64 + mt * 16 + lo) * 36 + hi * 8];
#pragma unroll
      for (int nt = 0; nt < 4; ++nt)
        bf[nt] = *(const short8*)&Fsh[(rr * 66 + nt * 16 + lo + dx + 1) * 36 + hi * 8];
#pragma unroll
      for (int mt = 0; mt < 4; ++mt)
#pragma unroll
        for (int nt = 0; nt < 4; ++nt)
          acc[mt][nt] = __builtin_amdgcn_mfma_f32_16x16x32_bf16(a[mt], bf[nt], acc[mt][nt], 0, 0, 0);
    }
  }
  const int y = 2 * iy + py;
#pragma unroll
  for (int mt = 0; mt < 4; ++mt) {
#pragma unroll
    for (int nt = 0; nt < 4; ++nt) {
#pragma unroll
      for (int r = 0; r < 4; ++r) {
        const int o = wm * 64 + mt * 16 + hi * 4 + r;
        const int xx = 2 * (nt * 16 + lo) + px;
        out[(((size_t)(b * OCH + o)) * 128 + y) * 128 + xx] = acc[mt][nt][r] + b_co[o];
      }
    }
  }
}

// ---------------------------------------------------------------------------
extern "C" void kernel_launch(void* const* d_in, const int* in_sizes, int n_in,
                              void* d_out, int out_size, void* d_ws, size_t ws_size,
                              hipStream_t stream) {
  const float* x     = (const float*)d_in[0];
  const float* wq    = (const float*)d_in[1];
  const float* bq    = (const float*)d_in[2];
  const float* wv    = (const float*)d_in[3];
  const float* bv    = (const float*)d_in[4];
  const float* w1    = (const float*)d_in[5];
  const float* b1    = (const float*)d_in[6];
  const float* w2    = (const float*)d_in[7];
  const float* b2    = (const float*)d_in[8];
  const float* gamma = (const float*)d_in[9];
  const float* w_co  = (const float*)d_in[10];
  const float* b_co  = (const float*)d_in[11];
  float* out = (float*)d_out;
  (void)in_sizes; (void)n_in; (void)out_size; (void)ws_size;

  char* p = (char*)d_ws;
  unsigned short* xt      = (unsigned short*)p; p += (size_t)BN * NN * CC * 2;      // 8.4 MB
  unsigned short* q1b     = (unsigned short*)p; p += (size_t)BN * CC * NN * 2;      // 8.4 MB
  float*          q2      = (float*)p;          p += (size_t)BN * CR * NN * 4;      // 2 MB
  float*          psum    = (float*)p;          p += (size_t)BN * SEGS * NN * 4;    // 0.5 MB
  float*          part2   = (float*)p;          p += (size_t)1024 * 4;
  unsigned short* Qt      = (unsigned short*)p; p += (size_t)BN * NN * 32 * 2;      // 1 MB
  unsigned short* Kt      = (unsigned short*)p; p += (size_t)BN * NN * 32 * 2;      // 1 MB
  unsigned short* Vb      = (unsigned short*)p; p += (size_t)BN * CC * NN * 2;      // 8.4 MB
  float*          rcs     = (float*)p;          p += (size_t)BN * NN * 4;
  float*          spatial = (float*)p;          p += 256;
  unsigned short* wqb     = (unsigned short*)p; p += (size_t)CC * CC * 2;
  unsigned short* wvb     = (unsigned short*)p; p += (size_t)CC * CC * 2;
  unsigned short* wbf     = (unsigned short*)p; p += (size_t)4 * 4 * 128 * 256 * 2; // 1 MB
  unsigned short* fusb    = (unsigned short*)p; p += (size_t)BN * 66 * 66 * 256 * 2;// 8.9 MB
  unsigned short* rden    = (unsigned short*)p; p += (size_t)NN * NN * 2;           // 33.5 MB

  // border-zero padded fusion buffer
  hipMemsetAsync(fusb, 0, (size_t)BN * 66 * 66 * 256 * 2, stream);

  k_wcast<<<dim3(64, 2), 256, 0, stream>>>(wq, wv, wqb, wvb);
  k_xt<<<dim3(64, 4, 4), 256, 0, stream>>>(x, xt, part2);
  k_projm<<<dim3(128, 4, 2), 256, 0, stream>>>(xt, wqb, bq, wvb, bv, q1b, Vb);
  k_adj1<<<dim3(256), 256, 0, stream>>>(q1b, w1, b1, q2);
  k_adj2<<<dim3(64, 4), 256, 0, stream>>>(q2, w2, b2, Qt, Kt);
  k_spatial2<<<dim3(4), 256, 0, stream>>>(part2, spatial);
  k_colstatm<<<dim3(64, SEGS), 512, 0, stream>>>(Qt, Kt, psum);
  k_rsum<<<dim3(64), 256, 0, stream>>>(psum, rcs);
  k_aden<<<dim3(128, 8), 512, 0, stream>>>(Qt, Kt, rden);
  k_wprep<<<dim3(2048), 256, 0, stream>>>(w_co, wbf);
  k_fused7<<<dim3(512), 512, 0, stream>>>(Qt, Kt, Vb, rden, x, rcs, gamma, spatial, fusb);
  k_deconv<<<dim3(16, 16), 512, 0, stream>>>(fusb, wbf, b_co, out);
}

// Round 18
// 207.025 us; speedup vs baseline: 1.1710x; 1.0579x over previous
//
#include <hip/hip_runtime.h>

#define BN 4
#define CC 256
#define NN 4096
#define CR 32
#define OCH 128
#define SEGS 8

typedef float f32x4 __attribute__((ext_vector_type(4)));
typedef short short8 __attribute__((ext_vector_type(8)));
typedef unsigned short u16x8 __attribute__((ext_vector_type(8)));
typedef unsigned short u16x4 __attribute__((ext_vector_type(4)));

__device__ __forceinline__ unsigned short f2b(float f) {
  unsigned u = __builtin_bit_cast(unsigned, f);
  u += 0x7fff + ((u >> 16) & 1);
  return (unsigned short)(u >> 16);
}
__device__ __forceinline__ float b2f(unsigned short h) {
  unsigned u = ((unsigned)h) << 16;
  return __builtin_bit_cast(float, u);
}

// ---------------------------------------------------------------------------
// cast wq / wv to bf16
__global__ __launch_bounds__(256) void k_wcast(const float* __restrict__ wq,
    const float* __restrict__ wv, unsigned short* __restrict__ wqb,
    unsigned short* __restrict__ wvb) {
  const int gid = (blockIdx.x * 256 + threadIdx.x) * 4;
  const float* src = blockIdx.y ? wv : wq;
  unsigned short* dst = blockIdx.y ? wvb : wqb;
  const float4 v = *(const float4*)(src + gid);
  u16x4 o; o[0] = f2b(v.x); o[1] = f2b(v.y); o[2] = f2b(v.z); o[3] = f2b(v.w);
  *(u16x4*)(dst + gid) = o;
}

// ---------------------------------------------------------------------------
// transpose+cast x[b][c][n] f32 -> xt[b][n][c] bf16, fused partial spatial sum
__global__ __launch_bounds__(256) void k_xt(const float* __restrict__ x,
    unsigned short* __restrict__ xt, float* __restrict__ part2) {
  __shared__ unsigned short T[64][65];
  __shared__ float red[256];
  const int b = blockIdx.z, c0 = blockIdx.y * 64, n0 = blockIdx.x * 64;
  const int t = threadIdx.x;
  float s = 0.f;
  for (int idx = t; idx < 4096; idx += 256) {
    int i = idx >> 6, j = idx & 63;
    const float v = x[((size_t)(b * CC + c0 + i)) * NN + n0 + j];
    s += v;
    T[i][j] = f2b(v);
  }
  __syncthreads();
  for (int idx = t; idx < 4096; idx += 256) {
    int j = idx >> 6, i = idx & 63;
    xt[((size_t)(b * NN + n0 + j)) * CC + c0 + i] = T[i][j];
  }
  red[t] = s;
  __syncthreads();
  for (int d = 128; d > 0; d >>= 1) {
    if (t < d) red[t] += red[t + d];
    __syncthreads();
  }
  if (t == 0) part2[b * 256 + blockIdx.y * 64 + blockIdx.x] = red[0];
}

__global__ void k_spatial2(const float* __restrict__ part2, float* __restrict__ spatial) {
  const int b = blockIdx.x;
  const int t = threadIdx.x;
  __shared__ float red[256];
  red[t] = part2[b * 256 + t];
  __syncthreads();
  for (int d = 128; d > 0; d >>= 1) {
    if (t < d) red[t] += red[t + d];
    __syncthreads();
  }
  if (t == 0) spatial[b] = red[0] * (1.0f / ((float)CC * NN));
}

// ---------------------------------------------------------------------------
// MFMA projection GEMM: out[b][c][n] = bias[c] + sum_j W[c][j] xt[b][n][j]
__global__ __launch_bounds__(256) void k_projm(const unsigned short* __restrict__ xt,
    const unsigned short* __restrict__ wqb, const float* __restrict__ bq,
    const unsigned short* __restrict__ wvb, const float* __restrict__ bv,
    unsigned short* __restrict__ q1b, unsigned short* __restrict__ Vb) {
  const int b = blockIdx.y, n0 = blockIdx.x * 32, which = blockIdx.z;
  const unsigned short* W = which ? wvb : wqb;
  const float* bias = which ? bv : bq;
  unsigned short* out = which ? Vb : q1b;
  const int t = threadIdx.x;
  const int w = t >> 6, l = t & 63;
  const int lo = l & 15, hi = l >> 4;
  const int oc0 = w * 64;
  f32x4 acc[4][2];
#pragma unroll
  for (int ct = 0; ct < 4; ++ct)
#pragma unroll
    for (int nt = 0; nt < 2; ++nt) acc[ct][nt] = (f32x4){0.f, 0.f, 0.f, 0.f};
  const unsigned short* wb = W + (size_t)(oc0 + lo) * CC + hi * 8;
  const unsigned short* xb = xt + ((size_t)(b * NN + n0 + lo)) * CC + hi * 8;
#pragma unroll
  for (int k0 = 0; k0 < CC; k0 += 32) {
    short8 aw[4], bx[2];
#pragma unroll
    for (int ct = 0; ct < 4; ++ct) aw[ct] = *(const short8*)(wb + ct * 16 * CC + k0);
#pragma unroll
    for (int nt = 0; nt < 2; ++nt) bx[nt] = *(const short8*)(xb + nt * 16 * CC + k0);
#pragma unroll
    for (int ct = 0; ct < 4; ++ct)
#pragma unroll
      for (int nt = 0; nt < 2; ++nt)
        acc[ct][nt] = __builtin_amdgcn_mfma_f32_16x16x32_bf16(aw[ct], bx[nt], acc[ct][nt], 0, 0, 0);
  }
#pragma unroll
  for (int ct = 0; ct < 4; ++ct) {
#pragma unroll
    for (int r = 0; r < 4; ++r) {
      const int c = oc0 + ct * 16 + hi * 4 + r;
      const float bvv = bias[c];
#pragma unroll
      for (int nt = 0; nt < 2; ++nt)
        out[((size_t)(b * CC + c)) * NN + n0 + nt * 16 + lo] = f2b(acc[ct][nt][r] + bvv);
    }
  }
}

// ---------------------------------------------------------------------------
// grouped conv1d (bf16 in, f32 out), vectorized: thread = 8 consecutive n
__global__ __launch_bounds__(256) void k_adj1(const unsigned short* __restrict__ q1,
    const float* __restrict__ w1, const float* __restrict__ b1,
    float* __restrict__ q2) {
  const int gid = blockIdx.x * 256 + threadIdx.x;   // B*32*(N/8) = 65536
  const int n8 = gid & 511;
  const int o = (gid >> 9) & 31;
  const int b = gid >> 14;
  const int n0 = n8 * 8;
  const unsigned short* base = q1 + ((size_t)b * CC + o * 8) * NN;
  float accv[8];
  const float bias = b1[o];
#pragma unroll
  for (int j = 0; j < 8; ++j) accv[j] = bias;
#pragma unroll
  for (int i = 0; i < 8; ++i) {
    const unsigned short* r = base + (size_t)i * NN;
    const u16x8 v = *(const u16x8*)(r + n0);
    float f[10];
    f[0] = (n0 > 0) ? b2f(r[n0 - 1]) : 0.f;
#pragma unroll
    for (int j = 0; j < 8; ++j) f[j + 1] = b2f(v[j]);
    f[9] = (n0 + 8 < NN) ? b2f(r[n0 + 8]) : 0.f;
    const float wa = w1[o * 24 + i * 3 + 0];
    const float wb = w1[o * 24 + i * 3 + 1];
    const float wc = w1[o * 24 + i * 3 + 2];
#pragma unroll
    for (int j = 0; j < 8; ++j) accv[j] += wa * f[j] + wb * f[j + 1] + wc * f[j + 2];
  }
  float4* dst = (float4*)&q2[((size_t)b * CR + o) * NN + n0];
  dst[0] = make_float4(accv[0], accv[1], accv[2], accv[3]);
  dst[1] = make_float4(accv[4], accv[5], accv[6], accv[7]);
}

// ---------------------------------------------------------------------------
// conv1d 32->64ch, writes bf16 TRANSPOSED Qt[b][n][32] (pre-scaled by log2e),
// Kt[b][n][32]
__global__ __launch_bounds__(256) void k_adj2(const float* __restrict__ q2,
    const float* __restrict__ w2, const float* __restrict__ b2,
    unsigned short* __restrict__ Qt, unsigned short* __restrict__ Kt) {
  __shared__ float q2s[32][66];
  __shared__ float w2t[96][64];
  __shared__ float b2s[64];
  const int b = blockIdx.y, n0 = blockIdx.x * 64;
  const int t = threadIdx.x;
  for (int idx = t; idx < 32 * 66; idx += 256) {
    int c = idx / 66, nn = idx % 66;
    int n = n0 + nn - 1;
    q2s[c][nn] = (n >= 0 && n < NN) ? q2[((size_t)b * CR + c) * NN + n] : 0.f;
  }
  for (int idx = t; idx < 96 * 64; idx += 256) {
    int k = idx & 63, ct = idx >> 6;
    w2t[ct][k] = w2[k * 96 + ct];
  }
  if (t < 64) b2s[t] = b2[t];
  __syncthreads();
  const int nn = t & 63, kh = t >> 6;
  float acc[16];
#pragma unroll
  for (int i = 0; i < 16; ++i) acc[i] = b2s[kh * 16 + i];
  for (int c = 0; c < 32; ++c) {
    const float x0 = q2s[c][nn], x1 = q2s[c][nn + 1], x2 = q2s[c][nn + 2];
    const float* wa = &w2t[c * 3 + 0][kh * 16];
    const float* wb = &w2t[c * 3 + 1][kh * 16];
    const float* wc = &w2t[c * 3 + 2][kh * 16];
#pragma unroll
    for (int i = 0; i < 16; ++i)
      acc[i] += wa[i] * x0 + wb[i] * x1 + wc[i] * x2;
  }
  const size_t row = ((size_t)b * NN + n0 + nn) * 32;
  u16x8 qo, ko;
#pragma unroll
  for (int i = 0; i < 8; ++i) {
    qo[i] = f2b(acc[2 * i] * 1.44269504f);   // fold log2(e) into Q
    ko[i] = f2b(acc[2 * i + 1]);
  }
  *(u16x8*)(Qt + row + kh * 8) = qo;
  *(u16x8*)(Kt + row + kh * 8) = ko;
}

// ---------------------------------------------------------------------------
// Merged S-producer: column exp-sums (register-accumulated) AND
// rden = rcp(sum_b exp2(S_b)) in consumer-tile layout (single S computation).
// grid (64 m-tiles, 8 n-segs), 512 thr = 8 waves (mt = w&3, nt2 = w>>2).
// Lane element (pos,r): n = seg*512+ch*64+(nt2*2+pos)*16+hi*4+r, m = m0+mt*16+lo.
__global__ __launch_bounds__(512) void k_colstatm(const unsigned short* __restrict__ Qt,
    const unsigned short* __restrict__ Kt, float* __restrict__ psum,
    unsigned short* __restrict__ rden) {
  __shared__ float CS[2][4][64];
  __shared__ unsigned short RD[2][2048];   // 8 KB per-chunk rden tile pair
  const int m0 = blockIdx.x * 64, seg = blockIdx.y;
  const int bx = blockIdx.x;
  const int t = threadIdx.x;
  const int w = t >> 6, l = t & 63;
  const int lo = l & 15, hi = l >> 4;
  const int mt = w & 3, nt2 = w >> 2;
  const f32x4 zero4 = (f32x4){0.f, 0.f, 0.f, 0.f};
  short8 kf[4];
#pragma unroll
  for (int bb = 0; bb < 4; ++bb)
    kf[bb] = *(const short8*)(Kt + ((size_t)(bb * NN + m0 + mt * 16 + lo)) * 32 + hi * 8);
  float colacc[4] = {0.f, 0.f, 0.f, 0.f};
  // per-(pos) RD slot base: idx = mt*512 + pos*256 + (lo>>2)*64 + (hi*4+r)*4 + (lo&3)
  const int rd_base = mt * 512 + (lo >> 2) * 64 + hi * 16 + (lo & 3);
  for (int ch = 0; ch < 8; ++ch) {
    const int nb = seg * 512 + ch * 64;
#pragma unroll
    for (int pos = 0; pos < 2; ++pos) {
      short8 qf[4];
#pragma unroll
      for (int bb = 0; bb < 4; ++bb)
        qf[bb] = *(const short8*)(Qt + ((size_t)(bb * NN + nb + (nt2 * 2 + pos) * 16 + lo)) * 32 + hi * 8);
      f32x4 s[4];
#pragma unroll
      for (int bb = 0; bb < 4; ++bb)
        s[bb] = __builtin_amdgcn_mfma_f32_16x16x32_bf16(qf[bb], kf[bb], zero4, 0, 0, 0);
      const int u = nt2 * 2 + pos;
      unsigned short* rdp = &RD[u >> 1][(u & 1) * 256 + rd_base];
#pragma unroll
      for (int r = 0; r < 4; ++r) {
        const float e0 = __builtin_amdgcn_exp2f(fminf(s[0][r], 86.f));
        const float e1 = __builtin_amdgcn_exp2f(fminf(s[1][r], 86.f));
        const float e2 = __builtin_amdgcn_exp2f(fminf(s[2][r], 86.f));
        const float e3 = __builtin_amdgcn_exp2f(fminf(s[3][r], 86.f));
        colacc[0] += e0; colacc[1] += e1; colacc[2] += e2; colacc[3] += e3;
        rdp[r * 4] = f2b(__builtin_amdgcn_rcpf(e0 + e1 + e2 + e3));
      }
    }
    __syncthreads();   // RD tile complete
    // coalesced copy-out: 2 tiles of 2048 u16; ntile = seg*16 + ch*2 + th
    {
      const int uu = t * 8;                 // 0..4088
      const int th = uu >> 11, off = uu & 2047;
      const size_t gbase = ((size_t)((seg * 16 + ch * 2 + th) * 64 + bx)) * 2048;
      *(u16x8*)(rden + gbase + off) = *(const u16x8*)&RD[th][off];
    }
    __syncthreads();   // RD reusable
  }
#pragma unroll
  for (int bb = 0; bb < 4; ++bb) {
    colacc[bb] += __shfl_xor(colacc[bb], 16, 64);
    colacc[bb] += __shfl_xor(colacc[bb], 32, 64);
  }
  if (hi == 0) {
#pragma unroll
    for (int bb = 0; bb < 4; ++bb) CS[nt2][bb][mt * 16 + lo] = colacc[bb];
  }
  __syncthreads();
  if (t < 256) {
    const int bb = t >> 6, mm = t & 63;
    psum[((size_t)(bb * SEGS + seg)) * NN + m0 + mm] = CS[0][bb][mm] + CS[1][bb][mm];
  }
}

__global__ void k_rsum(const float* __restrict__ psum, float* __restrict__ rcs) {
  const int gid = blockIdx.x * 256 + threadIdx.x;  // B*N = 16384
  const int b = gid >> 12, m = gid & (NN - 1);
  float S = 0.f;
#pragma unroll
  for (int s = 0; s < SEGS; ++s) S += psum[((size_t)(b * SEGS + s)) * NN + m];
  rcs[gid] = 1.0f / S;
}

// ---------------------------------------------------------------------------
// Fused attention v15: batch-redundancy removed. Per chunk: 1 kf load,
// 1 S-MFMA (own batch), coalesced u16x4 rden read, 1 exp per element.
// Vs per-wave single-buffer write-late; As dbuf + 1 barrier/chunk.
__global__ __launch_bounds__(512, 6) void k_fused7(const unsigned short* __restrict__ Qt,
    const unsigned short* __restrict__ Kt, const unsigned short* __restrict__ Vb,
    const unsigned short* __restrict__ rden, const float* __restrict__ x,
    const float* __restrict__ rcs, const float* __restrict__ gamma,
    const float* __restrict__ spatial, unsigned short* __restrict__ fusb) {
  __shared__ unsigned short Pool[256 * 64 + 2 * 2304];  // Vs 32KB + As dbuf 9.2KB
  unsigned short* VsB = Pool;
  unsigned short* AsB = Pool + 256 * 64;
  const int id = blockIdx.x;
  const int b = (id & 7) >> 1;                   // batch pinned to XCD pair
  const int ntile = ((id >> 3) << 1) | (id & 1); // 0..127
  const int n0 = ntile * 32;
  const int t = threadIdx.x;
  const int w = t >> 6, l = t & 63;
  const int lo = l & 15, hi = l >> 4;
  const int mt = w & 3, ns = w >> 2;             // S role: 16m x 16n tile
  const f32x4 zero4 = (f32x4){0.f, 0.f, 0.f, 0.f};
  unsigned short* Vsw = VsB + w * 2048;          // per-wave 32c x 64m slice

  const short8 qf = *(const short8*)(Qt + ((size_t)(b * NN + n0 + ns * 16 + lo)) * 32 + hi * 8);

  f32x4 acc[2][2];
#pragma unroll
  for (int ct = 0; ct < 2; ++ct)
#pragma unroll
    for (int nt = 0; nt < 2; ++nt) acc[ct][nt] = zero4;

  const int cl_base = l >> 3, jj = l & 7;
  const unsigned short* vwave = Vb + ((size_t)(b * CC + w * 32)) * NN;
  const unsigned short* kbase = Kt + ((size_t)(b * NN + mt * 16 + lo)) * 32 + hi * 8;
  const unsigned short* rdbase = rden + ((size_t)ntile * 64) * 2048
                               + (size_t)((mt * 2 + ns) * 64 + hi * 16 + lo) * 4;
  const float* rcs_b = rcs + b * NN;
  const int as_off = (ns * 16 + lo) * 72 + mt * 16 + hi * 4;  // u16x4 slot

  // ---- prologue: chunk 0 -> Vs + As buf0; kf prefetched for chunk 1
  short8 kf = *(const short8*)(kbase);
  {
    u16x8 vst[4];
#pragma unroll
    for (int q = 0; q < 4; ++q) {
      const int cl = q * 8 + cl_base;
      vst[q] = *(const u16x8*)(vwave + (size_t)cl * NN + jj * 8);
    }
    const u16x4 rd4 = *(const u16x4*)(rdbase);
    const f32x4 s = __builtin_amdgcn_mfma_f32_16x16x32_bf16(kf, qf, zero4, 0, 0, 0);
    const f32x4 rc4 = *(const f32x4*)(rcs_b + mt * 16 + hi * 4);
    u16x4 av;
#pragma unroll
    for (int r = 0; r < 4; ++r) {
      const float e = __builtin_amdgcn_exp2f(fminf(s[r], 86.f));
      av[r] = f2b(e * (b2f(rd4[r]) + rc4[r]));
    }
    *(u16x4*)&AsB[as_off] = av;
#pragma unroll
    for (int q = 0; q < 4; ++q) {
      const int cl = q * 8 + cl_base;
      *(u16x8*)&Vsw[cl * 64 + ((jj ^ (cl & 7)) << 3)] = vst[q];
    }
    kf = *(const short8*)(kbase + (size_t)64 * 32);
  }
  __syncthreads();

  for (int ch = 0; ch < 64; ++ch) {
    const int cur = ch & 1;
    unsigned short* Asc = AsB + cur * 2304;
    unsigned short* Asn = AsB + (cur ^ 1) * 2304;
    u16x8 vst[4];
    u16x4 av;
    if (ch < 63) {
      const int m1 = (ch + 1) * 64;
#pragma unroll
      for (int q = 0; q < 4; ++q) {
        const int cl = q * 8 + cl_base;
        vst[q] = *(const u16x8*)(vwave + (size_t)cl * NN + m1 + jj * 8);
      }
      const u16x4 rd4 = *(const u16x4*)(rdbase + (size_t)(ch + 1) * 2048);
      const f32x4 s = __builtin_amdgcn_mfma_f32_16x16x32_bf16(kf, qf, zero4, 0, 0, 0);
      const f32x4 rc4 = *(const f32x4*)(rcs_b + m1 + mt * 16 + hi * 4);
#pragma unroll
      for (int r = 0; r < 4; ++r) {
        const float e = __builtin_amdgcn_exp2f(fminf(s[r], 86.f));
        av[r] = f2b(e * (b2f(rd4[r]) + rc4[r]));
      }
      const int m2 = (ch < 62) ? (m1 + 64) : m1;
      kf = *(const short8*)(kbase + (size_t)m2 * 32);
    }
    // ---- PV(ch): wave-private Vs + shared Asc
#pragma unroll
    for (int kt = 0; kt < 2; ++kt) {
      short8 af[2];
#pragma unroll
      for (int nt = 0; nt < 2; ++nt)
        af[nt] = *(const short8*)&Asc[(nt * 16 + lo) * 72 + kt * 32 + hi * 8];
#pragma unroll
      for (int ct = 0; ct < 2; ++ct) {
        const int cl = ct * 16 + lo;
        const short8 vf = *(const short8*)&Vsw[cl * 64 + (((kt * 4 + hi) ^ (cl & 7)) << 3)];
#pragma unroll
        for (int nt = 0; nt < 2; ++nt)
          acc[ct][nt] = __builtin_amdgcn_mfma_f32_16x16x32_bf16(vf, af[nt], acc[ct][nt], 0, 0, 0);
      }
    }
    // ---- write-late: next-chunk V (own slice) + As
    if (ch < 63) {
#pragma unroll
      for (int q = 0; q < 4; ++q) {
        const int cl = q * 8 + cl_base;
        *(u16x8*)&Vsw[cl * 64 + ((jj ^ (cl & 7)) << 3)] = vst[q];
      }
      *(u16x4*)&Asn[as_off] = av;
    }
    __syncthreads();
  }

  // ---- epilogue: gamma*mean*acc + x -> Fs (reuse pool) -> coalesced fusb
  unsigned short* Fs = Pool;
  const float g = gamma[0] * spatial[b];
#pragma unroll
  for (int ct = 0; ct < 2; ++ct) {
#pragma unroll
    for (int nt = 0; nt < 2; ++nt) {
      u16x4 o4;
#pragma unroll
      for (int r = 0; r < 4; ++r) {
        const int c = w * 32 + ct * 16 + hi * 4 + r;
        const float xv = x[((size_t)(b * CC + c)) * NN + n0 + nt * 16 + lo];
        o4[r] = f2b(g * acc[ct][nt][r] + xv);
      }
      *(u16x4*)&Fs[(nt * 16 + lo) * 264 + w * 32 + ct * 16 + hi * 4] = o4;
    }
  }
  __syncthreads();
  const int iy = n0 >> 6, ix0 = n0 & 63;
  unsigned short* fb = fusb + (((size_t)(b * 66 + iy + 1)) * 66 + ix0 + 1) * 256;
#pragma unroll
  for (int q = 0; q < 2; ++q) {
    const int u = t + q * 512;               // 0..1023
    const int nl = u >> 5, c0 = (u & 31) * 8;
    *(u16x8*)(fb + (size_t)nl * 256 + c0) = *(const u16x8*)&Fs[nl * 264 + c0];
  }
}

// ---------------------------------------------------------------------------
// weight transform: wbf[p][tap][o][ic] (bf16, ic contiguous)
__global__ void k_wprep(const float* __restrict__ w_co, unsigned short* __restrict__ wbf) {
  const int gid = blockIdx.x * 256 + threadIdx.x;
  const int ic = gid & 255;
  const int o = (gid >> 8) & 127;
  const int tap = (gid >> 15) & 3;
  const int p = gid >> 17;
  const int py = p >> 1, px = p & 1;
  const int tyi = tap >> 1, txi = tap & 1;
  const int ky = py + 2 * tyi, kx = px + 2 * txi;
  wbf[gid] = f2b(w_co[(ic * 128 + o) * 16 + (3 - ky) * 4 + (3 - kx)]);
}

// ---------------------------------------------------------------------------
// MFMA transposed conv v3: LDS-staged F rows + weight panels per 32-ic chunk.
__global__ __launch_bounds__(512) void k_deconv(const unsigned short* __restrict__ fusb,
    const unsigned short* __restrict__ wbf, const float* __restrict__ b_co,
    float* __restrict__ out) {
  __shared__ unsigned short Fsh[5 * 66 * 36];    // 23.8 KB
  __shared__ unsigned short Wsh[4 * 128 * 36];   // 36.9 KB
  const int bp = blockIdx.y;
  const int b = bp >> 2, py = (bp >> 1) & 1, px = bp & 1;
  const int t = threadIdx.x;
  const int w = t >> 6, l = t & 63;
  const int lo = l & 15, hi = l >> 4;
  const int wm = w & 1, wrow = w >> 1;
  const int iy0 = blockIdx.x * 4;
  const int iy = iy0 + wrow;
  f32x4 acc[4][4];
#pragma unroll
  for (int mt = 0; mt < 4; ++mt)
#pragma unroll
    for (int nt = 0; nt < 4; ++nt) acc[mt][nt] = (f32x4){0.f, 0.f, 0.f, 0.f};
  const unsigned short* wp_base = wbf + (size_t)(bp & 3) * 4 * 128 * 256;
  const size_t frow0 = (size_t)(b * 66 + iy0 + py) * 66;

  for (int ic0 = 0; ic0 < 256; ic0 += 32) {
    __syncthreads();
#pragma unroll
    for (int pass = 0; pass < 3; ++pass) {
      const int idx = t + pass * 512;
      if (idx < 1320) {
        const int rr = idx / 264, rem = idx % 264;
        const int xxp = rem >> 2, h = rem & 3;
        const u16x8 v = *(const u16x8*)(fusb + (frow0 + (size_t)rr * 66 + xxp) * 256 + ic0 + h * 8);
        *(u16x8*)&Fsh[(rr * 66 + xxp) * 36 + h * 8] = v;
      }
    }
#pragma unroll
    for (int pass = 0; pass < 4; ++pass) {
      const int idx = t + pass * 512;
      const int tap = idx >> 9, o = (idx >> 2) & 127, h = idx & 3;
      const u16x8 v = *(const u16x8*)(wp_base + (size_t)tap * 32768 + (size_t)o * 256 + ic0 + h * 8);
      *(u16x8*)&Wsh[(tap * 128 + o) * 36 + h * 8] = v;
    }
    __syncthreads();
#pragma unroll
    for (int tap = 0; tap < 4; ++tap) {
      const int tyi = tap >> 1, txi = tap & 1;
      const int dx = px + txi - 1;
      const int rr = wrow + tyi;
      short8 a[4], bf[4];
#pragma unroll
      for (int mt = 0; mt < 4; ++mt)
        a[mt] = *(const short8*)&Wsh[(tap * 128 + wm * 64 + mt * 16 + lo) * 36 + hi * 8];
#pragma unroll
      for (int nt = 0; nt < 4; ++nt)
        bf[nt] = *(const short8*)&Fsh[(rr * 66 + nt * 16 + lo + dx + 1) * 36 + hi * 8];
#pragma unroll
      for (int mt = 0; mt < 4; ++mt)
#pragma unroll
        for (int nt = 0; nt < 4; ++nt)
          acc[mt][nt] = __builtin_amdgcn_mfma_f32_16x16x32_bf16(a[mt], bf[nt], acc[mt][nt], 0, 0, 0);
    }
  }
  const int y = 2 * iy + py;
#pragma unroll
  for (int mt = 0; mt < 4; ++mt) {
#pragma unroll
    for (int nt = 0; nt < 4; ++nt) {
#pragma unroll
      for (int r = 0; r < 4; ++r) {
        const int o = wm * 64 + mt * 16 + hi * 4 + r;
        const int xx = 2 * (nt * 16 + lo) + px;
        out[(((size_t)(b * OCH + o)) * 128 + y) * 128 + xx] = acc[mt][nt][r] + b_co[o];
      }
    }
  }
}

// ---------------------------------------------------------------------------
extern "C" void kernel_launch(void* const* d_in, const int* in_sizes, int n_in,
                              void* d_out, int out_size, void* d_ws, size_t ws_size,
                              hipStream_t stream) {
  const float* x     = (const float*)d_in[0];
  const float* wq    = (const float*)d_in[1];
  const float* bq    = (const float*)d_in[2];
  const float* wv    = (const float*)d_in[3];
  const float* bv    = (const float*)d_in[4];
  const float* w1    = (const float*)d_in[5];
  const float* b1    = (const float*)d_in[6];
  const float* w2    = (const float*)d_in[7];
  const float* b2    = (const float*)d_in[8];
  const float* gamma = (const float*)d_in[9];
  const float* w_co  = (const float*)d_in[10];
  const float* b_co  = (const float*)d_in[11];
  float* out = (float*)d_out;
  (void)in_sizes; (void)n_in; (void)out_size; (void)ws_size;

  char* p = (char*)d_ws;
  unsigned short* xt      = (unsigned short*)p; p += (size_t)BN * NN * CC * 2;      // 8.4 MB
  unsigned short* q1b     = (unsigned short*)p; p += (size_t)BN * CC * NN * 2;      // 8.4 MB
  float*          q2      = (float*)p;          p += (size_t)BN * CR * NN * 4;      // 2 MB
  float*          psum    = (float*)p;          p += (size_t)BN * SEGS * NN * 4;    // 0.5 MB
  float*          part2   = (float*)p;          p += (size_t)1024 * 4;
  unsigned short* Qt      = (unsigned short*)p; p += (size_t)BN * NN * 32 * 2;      // 1 MB
  unsigned short* Kt      = (unsigned short*)p; p += (size_t)BN * NN * 32 * 2;      // 1 MB
  unsigned short* Vb      = (unsigned short*)p; p += (size_t)BN * CC * NN * 2;      // 8.4 MB
  float*          rcs     = (float*)p;          p += (size_t)BN * NN * 4;
  float*          spatial = (float*)p;          p += 256;
  unsigned short* wqb     = (unsigned short*)p; p += (size_t)CC * CC * 2;
  unsigned short* wvb     = (unsigned short*)p; p += (size_t)CC * CC * 2;
  unsigned short* wbf     = (unsigned short*)p; p += (size_t)4 * 4 * 128 * 256 * 2; // 1 MB
  unsigned short* fusb    = (unsigned short*)p; p += (size_t)BN * 66 * 66 * 256 * 2;// 8.9 MB
  unsigned short* rden    = (unsigned short*)p; p += (size_t)NN * NN * 2;           // 33.5 MB

  // border-zero padded fusion buffer
  hipMemsetAsync(fusb, 0, (size_t)BN * 66 * 66 * 256 * 2, stream);

  k_wcast<<<dim3(64, 2), 256, 0, stream>>>(wq, wv, wqb, wvb);
  k_xt<<<dim3(64, 4, 4), 256, 0, stream>>>(x, xt, part2);
  k_projm<<<dim3(128, 4, 2), 256, 0, stream>>>(xt, wqb, bq, wvb, bv, q1b, Vb);
  k_adj1<<<dim3(256), 256, 0, stream>>>(q1b, w1, b1, q2);
  k_adj2<<<dim3(64, 4), 256, 0, stream>>>(q2, w2, b2, Qt, Kt);
  k_spatial2<<<dim3(4), 256, 0, stream>>>(part2, spatial);
  k_colstatm<<<dim3(64, SEGS), 512, 0, stream>>>(Qt, Kt, psum, rden);
  k_rsum<<<dim3(64), 256, 0, stream>>>(psum, rcs);
  k_wprep<<<dim3(2048), 256, 0, stream>>>(w_co, wbf);
  k_fused7<<<dim3(512), 512, 0, stream>>>(Qt, Kt, Vb, rden, x, rcs, gamma, spatial, fusb);
  k_deconv<<<dim3(16, 16), 512, 0, stream>>>(fusb, wbf, b_co, out);
}

// Round 19
// 203.742 us; speedup vs baseline: 1.1898x; 1.0161x over previous
//
#include <hip/hip_runtime.h>

#define BN 4
#define CC 256
#define NN 4096
#define CR 32
#define OCH 128
#define SEGS 8

typedef float f32x4 __attribute__((ext_vector_type(4)));
typedef short short8 __attribute__((ext_vector_type(8)));
typedef unsigned short u16x8 __attribute__((ext_vector_type(8)));
typedef unsigned short u16x4 __attribute__((ext_vector_type(4)));

__device__ __forceinline__ unsigned short f2b(float f) {
  unsigned u = __builtin_bit_cast(unsigned, f);
  u += 0x7fff + ((u >> 16) & 1);
  return (unsigned short)(u >> 16);
}
__device__ __forceinline__ float b2f(unsigned short h) {
  unsigned u = ((unsigned)h) << 16;
  return __builtin_bit_cast(float, u);
}

// ---------------------------------------------------------------------------
// merged weight prep: blocks 0..2047 transform w_co -> wbf (bf16, ic-contig);
// blocks 2048..2175 cast wq/wv -> bf16
__global__ __launch_bounds__(256) void k_wprep2(const float* __restrict__ w_co,
    const float* __restrict__ wq, const float* __restrict__ wv,
    unsigned short* __restrict__ wqb, unsigned short* __restrict__ wvb,
    unsigned short* __restrict__ wbf) {
  const int bid = blockIdx.x;
  const int t = threadIdx.x;
  if (bid < 2048) {
    const int gid = bid * 256 + t;
    const int ic = gid & 255;
    const int o = (gid >> 8) & 127;
    const int tap = (gid >> 15) & 3;
    const int p = gid >> 17;
    const int py = p >> 1, px = p & 1;
    const int tyi = tap >> 1, txi = tap & 1;
    const int ky = py + 2 * tyi, kx = px + 2 * txi;
    wbf[gid] = f2b(w_co[(ic * 128 + o) * 16 + (3 - ky) * 4 + (3 - kx)]);
  } else {
    const int bid2 = bid - 2048;              // 0..127
    const int y = bid2 >> 6, bx = bid2 & 63;
    const int gid = (bx * 256 + t) * 4;
    const float* src = y ? wv : wq;
    unsigned short* dst = y ? wvb : wqb;
    const float4 v = *(const float4*)(src + gid);
    u16x4 o4; o4[0] = f2b(v.x); o4[1] = f2b(v.y); o4[2] = f2b(v.z); o4[3] = f2b(v.w);
    *(u16x4*)(dst + gid) = o4;
  }
}

// ---------------------------------------------------------------------------
// transpose+cast x[b][c][n] f32 -> xt[b][n][c] bf16, fused partial spatial sum
__global__ __launch_bounds__(256) void k_xt(const float* __restrict__ x,
    unsigned short* __restrict__ xt, float* __restrict__ part2) {
  __shared__ unsigned short T[64][65];
  __shared__ float red[256];
  const int b = blockIdx.z, c0 = blockIdx.y * 64, n0 = blockIdx.x * 64;
  const int t = threadIdx.x;
  float s = 0.f;
  for (int idx = t; idx < 4096; idx += 256) {
    int i = idx >> 6, j = idx & 63;
    const float v = x[((size_t)(b * CC + c0 + i)) * NN + n0 + j];
    s += v;
    T[i][j] = f2b(v);
  }
  __syncthreads();
  for (int idx = t; idx < 4096; idx += 256) {
    int j = idx >> 6, i = idx & 63;
    xt[((size_t)(b * NN + n0 + j)) * CC + c0 + i] = T[i][j];
  }
  red[t] = s;
  __syncthreads();
  for (int d = 128; d > 0; d >>= 1) {
    if (t < d) red[t] += red[t + d];
    __syncthreads();
  }
  if (t == 0) part2[b * 256 + blockIdx.y * 64 + blockIdx.x] = red[0];
}

// ---------------------------------------------------------------------------
// MFMA projection GEMM: out[b][c][n] = bias[c] + sum_j W[c][j] xt[b][n][j]
__global__ __launch_bounds__(256) void k_projm(const unsigned short* __restrict__ xt,
    const unsigned short* __restrict__ wqb, const float* __restrict__ bq,
    const unsigned short* __restrict__ wvb, const float* __restrict__ bv,
    unsigned short* __restrict__ q1b, unsigned short* __restrict__ Vb) {
  const int b = blockIdx.y, n0 = blockIdx.x * 32, which = blockIdx.z;
  const unsigned short* W = which ? wvb : wqb;
  const float* bias = which ? bv : bq;
  unsigned short* out = which ? Vb : q1b;
  const int t = threadIdx.x;
  const int w = t >> 6, l = t & 63;
  const int lo = l & 15, hi = l >> 4;
  const int oc0 = w * 64;
  f32x4 acc[4][2];
#pragma unroll
  for (int ct = 0; ct < 4; ++ct)
#pragma unroll
    for (int nt = 0; nt < 2; ++nt) acc[ct][nt] = (f32x4){0.f, 0.f, 0.f, 0.f};
  const unsigned short* wb = W + (size_t)(oc0 + lo) * CC + hi * 8;
  const unsigned short* xb = xt + ((size_t)(b * NN + n0 + lo)) * CC + hi * 8;
#pragma unroll
  for (int k0 = 0; k0 < CC; k0 += 32) {
    short8 aw[4], bx[2];
#pragma unroll
    for (int ct = 0; ct < 4; ++ct) aw[ct] = *(const short8*)(wb + ct * 16 * CC + k0);
#pragma unroll
    for (int nt = 0; nt < 2; ++nt) bx[nt] = *(const short8*)(xb + nt * 16 * CC + k0);
#pragma unroll
    for (int ct = 0; ct < 4; ++ct)
#pragma unroll
      for (int nt = 0; nt < 2; ++nt)
        acc[ct][nt] = __builtin_amdgcn_mfma_f32_16x16x32_bf16(aw[ct], bx[nt], acc[ct][nt], 0, 0, 0);
  }
#pragma unroll
  for (int ct = 0; ct < 4; ++ct) {
#pragma unroll
    for (int r = 0; r < 4; ++r) {
      const int c = oc0 + ct * 16 + hi * 4 + r;
      const float bvv = bias[c];
#pragma unroll
      for (int nt = 0; nt < 2; ++nt)
        out[((size_t)(b * CC + c)) * NN + n0 + nt * 16 + lo] = f2b(acc[ct][nt][r] + bvv);
    }
  }
}

// ---------------------------------------------------------------------------
// grouped conv1d (bf16 in, f32 out), vectorized: thread = 8 consecutive n
__global__ __launch_bounds__(256) void k_adj1(const unsigned short* __restrict__ q1,
    const float* __restrict__ w1, const float* __restrict__ b1,
    float* __restrict__ q2) {
  const int gid = blockIdx.x * 256 + threadIdx.x;   // B*32*(N/8) = 65536
  const int n8 = gid & 511;
  const int o = (gid >> 9) & 31;
  const int b = gid >> 14;
  const int n0 = n8 * 8;
  const unsigned short* base = q1 + ((size_t)b * CC + o * 8) * NN;
  float accv[8];
  const float bias = b1[o];
#pragma unroll
  for (int j = 0; j < 8; ++j) accv[j] = bias;
#pragma unroll
  for (int i = 0; i < 8; ++i) {
    const unsigned short* r = base + (size_t)i * NN;
    const u16x8 v = *(const u16x8*)(r + n0);
    float f[10];
    f[0] = (n0 > 0) ? b2f(r[n0 - 1]) : 0.f;
#pragma unroll
    for (int j = 0; j < 8; ++j) f[j + 1] = b2f(v[j]);
    f[9] = (n0 + 8 < NN) ? b2f(r[n0 + 8]) : 0.f;
    const float wa = w1[o * 24 + i * 3 + 0];
    const float wb = w1[o * 24 + i * 3 + 1];
    const float wc = w1[o * 24 + i * 3 + 2];
#pragma unroll
    for (int j = 0; j < 8; ++j) accv[j] += wa * f[j] + wb * f[j + 1] + wc * f[j + 2];
  }
  float4* dst = (float4*)&q2[((size_t)b * CR + o) * NN + n0];
  dst[0] = make_float4(accv[0], accv[1], accv[2], accv[3]);
  dst[1] = make_float4(accv[4], accv[5], accv[6], accv[7]);
}

// ---------------------------------------------------------------------------
// conv1d 32->64ch, writes bf16 TRANSPOSED Qt[b][n][32] (pre-scaled by log2e),
// Kt[b][n][32]
__global__ __launch_bounds__(256) void k_adj2(const float* __restrict__ q2,
    const float* __restrict__ w2, const float* __restrict__ b2,
    unsigned short* __restrict__ Qt, unsigned short* __restrict__ Kt) {
  __shared__ float q2s[32][66];
  __shared__ float w2t[96][64];
  __shared__ float b2s[64];
  const int b = blockIdx.y, n0 = blockIdx.x * 64;
  const int t = threadIdx.x;
  for (int idx = t; idx < 32 * 66; idx += 256) {
    int c = idx / 66, nn = idx % 66;
    int n = n0 + nn - 1;
    q2s[c][nn] = (n >= 0 && n < NN) ? q2[((size_t)b * CR + c) * NN + n] : 0.f;
  }
  for (int idx = t; idx < 96 * 64; idx += 256) {
    int k = idx & 63, ct = idx >> 6;
    w2t[ct][k] = w2[k * 96 + ct];
  }
  if (t < 64) b2s[t] = b2[t];
  __syncthreads();
  const int nn = t & 63, kh = t >> 6;
  float acc[16];
#pragma unroll
  for (int i = 0; i < 16; ++i) acc[i] = b2s[kh * 16 + i];
  for (int c = 0; c < 32; ++c) {
    const float x0 = q2s[c][nn], x1 = q2s[c][nn + 1], x2 = q2s[c][nn + 2];
    const float* wa = &w2t[c * 3 + 0][kh * 16];
    const float* wb = &w2t[c * 3 + 1][kh * 16];
    const float* wc = &w2t[c * 3 + 2][kh * 16];
#pragma unroll
    for (int i = 0; i < 16; ++i)
      acc[i] += wa[i] * x0 + wb[i] * x1 + wc[i] * x2;
  }
  const size_t row = ((size_t)b * NN + n0 + nn) * 32;
  u16x8 qo, ko;
#pragma unroll
  for (int i = 0; i < 8; ++i) {
    qo[i] = f2b(acc[2 * i] * 1.44269504f);   // fold log2(e) into Q
    ko[i] = f2b(acc[2 * i + 1]);
  }
  *(u16x8*)(Qt + row + kh * 8) = qo;
  *(u16x8*)(Kt + row + kh * 8) = ko;
}

// ---------------------------------------------------------------------------
// Merged S-producer: column exp-sums (register-accumulated) AND
// rden = rcp(sum_b exp2(S_b)) in consumer-tile layout (single S computation).
__global__ __launch_bounds__(512) void k_colstatm(const unsigned short* __restrict__ Qt,
    const unsigned short* __restrict__ Kt, float* __restrict__ psum,
    unsigned short* __restrict__ rden) {
  __shared__ float CS[2][4][64];
  __shared__ unsigned short RD[2][2048];   // 8 KB per-chunk rden tile pair
  const int m0 = blockIdx.x * 64, seg = blockIdx.y;
  const int bx = blockIdx.x;
  const int t = threadIdx.x;
  const int w = t >> 6, l = t & 63;
  const int lo = l & 15, hi = l >> 4;
  const int mt = w & 3, nt2 = w >> 2;
  const f32x4 zero4 = (f32x4){0.f, 0.f, 0.f, 0.f};
  short8 kf[4];
#pragma unroll
  for (int bb = 0; bb < 4; ++bb)
    kf[bb] = *(const short8*)(Kt + ((size_t)(bb * NN + m0 + mt * 16 + lo)) * 32 + hi * 8);
  float colacc[4] = {0.f, 0.f, 0.f, 0.f};
  const int rd_base = mt * 512 + (lo >> 2) * 64 + hi * 16 + (lo & 3);
  for (int ch = 0; ch < 8; ++ch) {
    const int nb = seg * 512 + ch * 64;
#pragma unroll
    for (int pos = 0; pos < 2; ++pos) {
      short8 qf[4];
#pragma unroll
      for (int bb = 0; bb < 4; ++bb)
        qf[bb] = *(const short8*)(Qt + ((size_t)(bb * NN + nb + (nt2 * 2 + pos) * 16 + lo)) * 32 + hi * 8);
      f32x4 s[4];
#pragma unroll
      for (int bb = 0; bb < 4; ++bb)
        s[bb] = __builtin_amdgcn_mfma_f32_16x16x32_bf16(qf[bb], kf[bb], zero4, 0, 0, 0);
      const int u = nt2 * 2 + pos;
      unsigned short* rdp = &RD[u >> 1][(u & 1) * 256 + rd_base];
#pragma unroll
      for (int r = 0; r < 4; ++r) {
        const float e0 = __builtin_amdgcn_exp2f(fminf(s[0][r], 86.f));
        const float e1 = __builtin_amdgcn_exp2f(fminf(s[1][r], 86.f));
        const float e2 = __builtin_amdgcn_exp2f(fminf(s[2][r], 86.f));
        const float e3 = __builtin_amdgcn_exp2f(fminf(s[3][r], 86.f));
        colacc[0] += e0; colacc[1] += e1; colacc[2] += e2; colacc[3] += e3;
        rdp[r * 4] = f2b(__builtin_amdgcn_rcpf(e0 + e1 + e2 + e3));
      }
    }
    __syncthreads();   // RD tile complete
    {
      const int uu = t * 8;                 // 0..4088
      const int th = uu >> 11, off = uu & 2047;
      const size_t gbase = ((size_t)((seg * 16 + ch * 2 + th) * 64 + bx)) * 2048;
      *(u16x8*)(rden + gbase + off) = *(const u16x8*)&RD[th][off];
    }
    __syncthreads();   // RD reusable
  }
#pragma unroll
  for (int bb = 0; bb < 4; ++bb) {
    colacc[bb] += __shfl_xor(colacc[bb], 16, 64);
    colacc[bb] += __shfl_xor(colacc[bb], 32, 64);
  }
  if (hi == 0) {
#pragma unroll
    for (int bb = 0; bb < 4; ++bb) CS[nt2][bb][mt * 16 + lo] = colacc[bb];
  }
  __syncthreads();
  if (t < 256) {
    const int bb = t >> 6, mm = t & 63;
    psum[((size_t)(bb * SEGS + seg)) * NN + m0 + mm] = CS[0][bb][mm] + CS[1][bb][mm];
  }
}

// ---------------------------------------------------------------------------
// merged: blocks 0..63 rsum (rcs = 1/colsum); blocks 64..67 spatial mean
__global__ __launch_bounds__(256) void k_rsum2(const float* __restrict__ psum,
    const float* __restrict__ part2, float* __restrict__ rcs,
    float* __restrict__ spatial) {
  const int bid = blockIdx.x;
  const int t = threadIdx.x;
  if (bid < 64) {
    const int gid = bid * 256 + t;  // B*N = 16384
    const int b = gid >> 12, m = gid & (NN - 1);
    float S = 0.f;
#pragma unroll
    for (int s = 0; s < SEGS; ++s) S += psum[((size_t)(b * SEGS + s)) * NN + m];
    rcs[gid] = 1.0f / S;
  } else {
    const int b = bid - 64;
    __shared__ float red[256];
    red[t] = part2[b * 256 + t];
    __syncthreads();
    for (int d = 128; d > 0; d >>= 1) {
      if (t < d) red[t] += red[t + d];
      __syncthreads();
    }
    if (t == 0) spatial[b] = red[0] * (1.0f / ((float)CC * NN));
  }
}

// ---------------------------------------------------------------------------
// Fused attention v16: as v15; residual read from xt (bf16 channels-last,
// XCD-local) instead of f32 x — drops ~59 MB HBM from the critical kernel.
__global__ __launch_bounds__(512, 6) void k_fused7(const unsigned short* __restrict__ Qt,
    const unsigned short* __restrict__ Kt, const unsigned short* __restrict__ Vb,
    const unsigned short* __restrict__ rden, const unsigned short* __restrict__ xt,
    const float* __restrict__ rcs, const float* __restrict__ gamma,
    const float* __restrict__ spatial, unsigned short* __restrict__ fusb) {
  __shared__ unsigned short Pool[256 * 64 + 2 * 2304];  // Vs 32KB + As dbuf 9.2KB
  unsigned short* VsB = Pool;
  unsigned short* AsB = Pool + 256 * 64;
  const int id = blockIdx.x;
  const int b = (id & 7) >> 1;                   // batch pinned to XCD pair
  const int ntile = ((id >> 3) << 1) | (id & 1); // 0..127
  const int n0 = ntile * 32;
  const int t = threadIdx.x;
  const int w = t >> 6, l = t & 63;
  const int lo = l & 15, hi = l >> 4;
  const int mt = w & 3, ns = w >> 2;             // S role: 16m x 16n tile
  const f32x4 zero4 = (f32x4){0.f, 0.f, 0.f, 0.f};
  unsigned short* Vsw = VsB + w * 2048;          // per-wave 32c x 64m slice

  const short8 qf = *(const short8*)(Qt + ((size_t)(b * NN + n0 + ns * 16 + lo)) * 32 + hi * 8);

  f32x4 acc[2][2];
#pragma unroll
  for (int ct = 0; ct < 2; ++ct)
#pragma unroll
    for (int nt = 0; nt < 2; ++nt) acc[ct][nt] = zero4;

  const int cl_base = l >> 3, jj = l & 7;
  const unsigned short* vwave = Vb + ((size_t)(b * CC + w * 32)) * NN;
  const unsigned short* kbase = Kt + ((size_t)(b * NN + mt * 16 + lo)) * 32 + hi * 8;
  const unsigned short* rdbase = rden + ((size_t)ntile * 64) * 2048
                               + (size_t)((mt * 2 + ns) * 64 + hi * 16 + lo) * 4;
  const float* rcs_b = rcs + b * NN;
  const int as_off = (ns * 16 + lo) * 72 + mt * 16 + hi * 4;  // u16x4 slot

  // ---- prologue: chunk 0 -> Vs + As buf0; kf prefetched for chunk 1
  short8 kf = *(const short8*)(kbase);
  {
    u16x8 vst[4];
#pragma unroll
    for (int q = 0; q < 4; ++q) {
      const int cl = q * 8 + cl_base;
      vst[q] = *(const u16x8*)(vwave + (size_t)cl * NN + jj * 8);
    }
    const u16x4 rd4 = *(const u16x4*)(rdbase);
    const f32x4 s = __builtin_amdgcn_mfma_f32_16x16x32_bf16(kf, qf, zero4, 0, 0, 0);
    const f32x4 rc4 = *(const f32x4*)(rcs_b + mt * 16 + hi * 4);
    u16x4 av;
#pragma unroll
    for (int r = 0; r < 4; ++r) {
      const float e = __builtin_amdgcn_exp2f(fminf(s[r], 86.f));
      av[r] = f2b(e * (b2f(rd4[r]) + rc4[r]));
    }
    *(u16x4*)&AsB[as_off] = av;
#pragma unroll
    for (int q = 0; q < 4; ++q) {
      const int cl = q * 8 + cl_base;
      *(u16x8*)&Vsw[cl * 64 + ((jj ^ (cl & 7)) << 3)] = vst[q];
    }
    kf = *(const short8*)(kbase + (size_t)64 * 32);
  }
  __syncthreads();

  for (int ch = 0; ch < 64; ++ch) {
    const int cur = ch & 1;
    unsigned short* Asc = AsB + cur * 2304;
    unsigned short* Asn = AsB + (cur ^ 1) * 2304;
    u16x8 vst[4];
    u16x4 av;
    if (ch < 63) {
      const int m1 = (ch + 1) * 64;
#pragma unroll
      for (int q = 0; q < 4; ++q) {
        const int cl = q * 8 + cl_base;
        vst[q] = *(const u16x8*)(vwave + (size_t)cl * NN + m1 + jj * 8);
      }
      const u16x4 rd4 = *(const u16x4*)(rdbase + (size_t)(ch + 1) * 2048);
      const f32x4 s = __builtin_amdgcn_mfma_f32_16x16x32_bf16(kf, qf, zero4, 0, 0, 0);
      const f32x4 rc4 = *(const f32x4*)(rcs_b + m1 + mt * 16 + hi * 4);
#pragma unroll
      for (int r = 0; r < 4; ++r) {
        const float e = __builtin_amdgcn_exp2f(fminf(s[r], 86.f));
        av[r] = f2b(e * (b2f(rd4[r]) + rc4[r]));
      }
      const int m2 = (ch < 62) ? (m1 + 64) : m1;
      kf = *(const short8*)(kbase + (size_t)m2 * 32);
    }
    // ---- PV(ch): wave-private Vs + shared Asc
#pragma unroll
    for (int kt = 0; kt < 2; ++kt) {
      short8 af[2];
#pragma unroll
      for (int nt = 0; nt < 2; ++nt)
        af[nt] = *(const short8*)&Asc[(nt * 16 + lo) * 72 + kt * 32 + hi * 8];
#pragma unroll
      for (int ct = 0; ct < 2; ++ct) {
        const int cl = ct * 16 + lo;
        const short8 vf = *(const short8*)&Vsw[cl * 64 + (((kt * 4 + hi) ^ (cl & 7)) << 3)];
#pragma unroll
        for (int nt = 0; nt < 2; ++nt)
          acc[ct][nt] = __builtin_amdgcn_mfma_f32_16x16x32_bf16(vf, af[nt], acc[ct][nt], 0, 0, 0);
      }
    }
    // ---- write-late: next-chunk V (own slice) + As
    if (ch < 63) {
#pragma unroll
      for (int q = 0; q < 4; ++q) {
        const int cl = q * 8 + cl_base;
        *(u16x8*)&Vsw[cl * 64 + ((jj ^ (cl & 7)) << 3)] = vst[q];
      }
      *(u16x4*)&Asn[as_off] = av;
    }
    __syncthreads();
  }

  // ---- epilogue: gamma*mean*acc + xt(bf16) -> Fs -> coalesced fusb
  unsigned short* Fs = Pool;
  const float g = gamma[0] * spatial[b];
#pragma unroll
  for (int ct = 0; ct < 2; ++ct) {
#pragma unroll
    for (int nt = 0; nt < 2; ++nt) {
      const int n = n0 + nt * 16 + lo;
      const int c0 = w * 32 + ct * 16 + hi * 4;
      const u16x4 xv4 = *(const u16x4*)(xt + ((size_t)(b * NN + n)) * CC + c0);
      u16x4 o4;
#pragma unroll
      for (int r = 0; r < 4; ++r)
        o4[r] = f2b(g * acc[ct][nt][r] + b2f(xv4[r]));
      *(u16x4*)&Fs[(nt * 16 + lo) * 264 + c0] = o4;
    }
  }
  __syncthreads();
  const int iy = n0 >> 6, ix0 = n0 & 63;
  unsigned short* fb = fusb + (((size_t)(b * 66 + iy + 1)) * 66 + ix0 + 1) * 256;
#pragma unroll
  for (int q = 0; q < 2; ++q) {
    const int u = t + q * 512;               // 0..1023
    const int nl = u >> 5, c0 = (u & 31) * 8;
    *(u16x8*)(fb + (size_t)nl * 256 + c0) = *(const u16x8*)&Fs[nl * 264 + c0];
  }
}

// ---------------------------------------------------------------------------
// MFMA transposed conv v3: LDS-staged F rows + weight panels per 32-ic chunk.
__global__ __launch_bounds__(512) void k_deconv(const unsigned short* __restrict__ fusb,
    const unsigned short* __restrict__ wbf, const float* __restrict__ b_co,
    float* __restrict__ out) {
  __shared__ unsigned short Fsh[5 * 66 * 36];    // 23.8 KB
  __shared__ unsigned short Wsh[4 * 128 * 36];   // 36.9 KB
  const int bp = blockIdx.y;
  const int b = bp >> 2, py = (bp >> 1) & 1, px = bp & 1;
  const int t = threadIdx.x;
  const int w = t >> 6, l = t & 63;
  const int lo = l & 15, hi = l >> 4;
  const int wm = w & 1, wrow = w >> 1;
  const int iy0 = blockIdx.x * 4;
  const int iy = iy0 + wrow;
  f32x4 acc[4][4];
#pragma unroll
  for (int mt = 0; mt < 4; ++mt)
#pragma unroll
    for (int nt = 0; nt < 4; ++nt) acc[mt][nt] = (f32x4){0.f, 0.f, 0.f, 0.f};
  const unsigned short* wp_base = wbf + (size_t)(bp & 3) * 4 * 128 * 256;
  const size_t frow0 = (size_t)(b * 66 + iy0 + py) * 66;

  for (int ic0 = 0; ic0 < 256; ic0 += 32) {
    __syncthreads();
#pragma unroll
    for (int pass = 0; pass < 3; ++pass) {
      const int idx = t + pass * 512;
      if (idx < 1320) {
        const int rr = idx / 264, rem = idx % 264;
        const int xxp = rem >> 2, h = rem & 3;
        const u16x8 v = *(const u16x8*)(fusb + (frow0 + (size_t)rr * 66 + xxp) * 256 + ic0 + h * 8);
        *(u16x8*)&Fsh[(rr * 66 + xxp) * 36 + h * 8] = v;
      }
    }
#pragma unroll
    for (int pass = 0; pass < 4; ++pass) {
      const int idx = t + pass * 512;
      const int tap = idx >> 9, o = (idx >> 2) & 127, h = idx & 3;
      const u16x8 v = *(const u16x8*)(wp_base + (size_t)tap * 32768 + (size_t)o * 256 + ic0 + h * 8);
      *(u16x8*)&Wsh[(tap * 128 + o) * 36 + h * 8] = v;
    }
    __syncthreads();
#pragma unroll
    for (int tap = 0; tap < 4; ++tap) {
      const int tyi = tap >> 1, txi = tap & 1;
      const int dx = px + txi - 1;
      const int rr = wrow + tyi;
      short8 a[4], bf[4];
#pragma unroll
      for (int mt = 0; mt < 4; ++mt)
        a[mt] = *(const short8*)&Wsh[(tap * 128 + wm * 64 + mt * 16 + lo) * 36 + hi * 8];
#pragma unroll
      for (int nt = 0; nt < 4; ++nt)
        bf[nt] = *(const short8*)&Fsh[(rr * 66 + nt * 16 + lo + dx + 1) * 36 + hi * 8];
#pragma unroll
      for (int mt = 0; mt < 4; ++mt)
#pragma unroll
        for (int nt = 0; nt < 4; ++nt)
          acc[mt][nt] = __builtin_amdgcn_mfma_f32_16x16x32_bf16(a[mt], bf[nt], acc[mt][nt], 0, 0, 0);
    }
  }
  const int y = 2 * iy + py;
#pragma unroll
  for (int mt = 0; mt < 4; ++mt) {
#pragma unroll
    for (int nt = 0; nt < 4; ++nt) {
#pragma unroll
      for (int r = 0; r < 4; ++r) {
        const int o = wm * 64 + mt * 16 + hi * 4 + r;
        const int xx = 2 * (nt * 16 + lo) + px;
        out[(((size_t)(b * OCH + o)) * 128 + y) * 128 + xx] = acc[mt][nt][r] + b_co[o];
      }
    }
  }
}

// ---------------------------------------------------------------------------
extern "C" void kernel_launch(void* const* d_in, const int* in_sizes, int n_in,
                              void* d_out, int out_size, void* d_ws, size_t ws_size,
                              hipStream_t stream) {
  const float* x     = (const float*)d_in[0];
  const float* wq    = (const float*)d_in[1];
  const float* bq    = (const float*)d_in[2];
  const float* wv    = (const float*)d_in[3];
  const float* bv    = (const float*)d_in[4];
  const float* w1    = (const float*)d_in[5];
  const float* b1    = (const float*)d_in[6];
  const float* w2    = (const float*)d_in[7];
  const float* b2    = (const float*)d_in[8];
  const float* gamma = (const float*)d_in[9];
  const float* w_co  = (const float*)d_in[10];
  const float* b_co  = (const float*)d_in[11];
  float* out = (float*)d_out;
  (void)in_sizes; (void)n_in; (void)out_size; (void)ws_size;

  char* p = (char*)d_ws;
  unsigned short* xt      = (unsigned short*)p; p += (size_t)BN * NN * CC * 2;      // 8.4 MB
  unsigned short* q1b     = (unsigned short*)p; p += (size_t)BN * CC * NN * 2;      // 8.4 MB
  float*          q2      = (float*)p;          p += (size_t)BN * CR * NN * 4;      // 2 MB
  float*          psum    = (float*)p;          p += (size_t)BN * SEGS * NN * 4;    // 0.5 MB
  float*          part2   = (float*)p;          p += (size_t)1024 * 4;
  unsigned short* Qt      = (unsigned short*)p; p += (size_t)BN * NN * 32 * 2;      // 1 MB
  unsigned short* Kt      = (unsigned short*)p; p += (size_t)BN * NN * 32 * 2;      // 1 MB
  unsigned short* Vb      = (unsigned short*)p; p += (size_t)BN * CC * NN * 2;      // 8.4 MB
  float*          rcs     = (float*)p;          p += (size_t)BN * NN * 4;
  float*          spatial = (float*)p;          p += 256;
  unsigned short* wqb     = (unsigned short*)p; p += (size_t)CC * CC * 2;
  unsigned short* wvb     = (unsigned short*)p; p += (size_t)CC * CC * 2;
  unsigned short* wbf     = (unsigned short*)p; p += (size_t)4 * 4 * 128 * 256 * 2; // 1 MB
  unsigned short* fusb    = (unsigned short*)p; p += (size_t)BN * 66 * 66 * 256 * 2;// 8.9 MB
  unsigned short* rden    = (unsigned short*)p; p += (size_t)NN * NN * 2;           // 33.5 MB

  // border-zero padded fusion buffer
  hipMemsetAsync(fusb, 0, (size_t)BN * 66 * 66 * 256 * 2, stream);

  k_wprep2<<<dim3(2176), 256, 0, stream>>>(w_co, wq, wv, wqb, wvb, wbf);
  k_xt<<<dim3(64, 4, 4), 256, 0, stream>>>(x, xt, part2);
  k_projm<<<dim3(128, 4, 2), 256, 0, stream>>>(xt, wqb, bq, wvb, bv, q1b, Vb);
  k_adj1<<<dim3(256), 256, 0, stream>>>(q1b, w1, b1, q2);
  k_adj2<<<dim3(64, 4), 256, 0, stream>>>(q2, w2, b2, Qt, Kt);
  k_colstatm<<<dim3(64, SEGS), 512, 0, stream>>>(Qt, Kt, psum, rden);
  k_rsum2<<<dim3(68), 256, 0, stream>>>(psum, part2, rcs, spatial);
  k_fused7<<<dim3(512), 512, 0, stream>>>(Qt, Kt, Vb, rden, xt, rcs, gamma, spatial, fusb);
  k_deconv<<<dim3(16, 16), 512, 0, stream>>>(fusb, wbf, b_co, out);
}